// Round 2
// baseline (298.041 us; speedup 1.0000x reference)
//
#include <hip/hip_runtime.h>

// Problem constants (fixed by setup_inputs)
#define BB 2
#define CC 256
#define HH 100
#define WW 100
#define NROI 512
#define KDIM 12544   // 49*256
#define FC 1024

typedef _Float16 half_t;
typedef _Float16 f16x2 __attribute__((ext_vector_type(2)));
typedef _Float16 f16x8 __attribute__((ext_vector_type(8)));
typedef _Float16 f16x4 __attribute__((ext_vector_type(4)));
typedef float f32x4 __attribute__((ext_vector_type(4)));

// ---------------- feat (B,C,H,W) fp32 -> featT (B,H*W,C) fp16 ----------------
__global__ __launch_bounds__(256) void transpose_feat(const float* __restrict__ feat,
                                                      half_t* __restrict__ featT) {
  __shared__ float tile[32][33];
  int b = blockIdx.z;
  int hw0 = blockIdx.x * 32;
  int c0 = blockIdx.y * 32;
  int tx = threadIdx.x, ty = threadIdx.y;
  const float* fb = feat + (size_t)b * CC * (HH * WW);
#pragma unroll
  for (int i = 0; i < 4; i++) {
    int c = c0 + ty + i * 8;
    int hw = hw0 + tx;
    tile[ty + i * 8][tx] = (hw < HH * WW) ? fb[(size_t)c * (HH * WW) + hw] : 0.0f;
  }
  __syncthreads();
  half_t* ob = featT + (size_t)b * (HH * WW) * CC;
#pragma unroll
  for (int i = 0; i < 4; i++) {
    int hw = hw0 + ty + i * 8;
    int c = c0 + tx;
    if (hw < HH * WW) ob[(size_t)hw * CC + c] = (half_t)tile[tx][ty + i * 8];
  }
}

// ---------------- fp32 -> fp16 convert (w1, w2) ----------------
__global__ __launch_bounds__(256) void convert_f32_f16(const float* __restrict__ in,
                                                       half_t* __restrict__ out, int n) {
  int i4 = (blockIdx.x * 256 + threadIdx.x) * 4;
  if (i4 < n) {
    float4 v = *(const float4*)(in + i4);
    f16x4 o;
    o[0] = (half_t)v.x; o[1] = (half_t)v.y; o[2] = (half_t)v.z; o[3] = (half_t)v.w;
    *(f16x4*)(out + i4) = o;
  }
}

// ---------------- deformable PSROI pooling, one block (512 thr) per ROI ----------------
struct PixW { int idx; float w; };

template <bool PASS2>
__global__ __launch_bounds__(512) void pool_kernel(const half_t* __restrict__ featT,
                                                   const float* __restrict__ rois,
                                                   const float* __restrict__ om,
                                                   half_t* __restrict__ xout,
                                                   float* __restrict__ out) {
  __shared__ PixW s_pix[49 * 28];
  __shared__ int s_cnt[49];
  __shared__ float s_scale[49];
  __shared__ float  s_outf[PASS2 ? KDIM : 1];
  __shared__ half_t s_outh[PASS2 ? 1 : KDIM];

  const int n = blockIdx.x;
  const int tid = threadIdx.x;
  const float* r = rois + n * 5;
  const int b = (int)r[0];
  const float rsw = rintf(r[1]) * 0.0625f - 0.5f;
  const float rsh = rintf(r[2]) * 0.0625f - 0.5f;
  const float rew = (rintf(r[3]) + 1.0f) * 0.0625f - 0.5f;
  const float reh = (rintf(r[4]) + 1.0f) * 0.0625f - 0.5f;
  const float roi_w = fmaxf(rew - rsw, 0.1f);
  const float roi_h = fmaxf(reh - rsh, 0.1f);
  const float bin_h = roi_h / 7.0f, bin_w = roi_w / 7.0f;
  const float sub_h = bin_h * 0.25f, sub_w = bin_w * 0.25f;
  const half_t* fb = featT + (size_t)b * (HH * WW) * CC;

  if (tid < 49) {
    const int p = tid, ph = p / 7, pw = p - ph * 7;
    float tx = 0.0f, ty = 0.0f, mask = 1.0f;
    if (PASS2) {
      tx = om[n * 147 + p] * 0.1f;
      ty = om[n * 147 + 49 + p] * 0.1f;
      mask = 1.0f / (1.0f + expf(-om[n * 147 + 98 + p]));
    }
    const float hst = (float)ph * bin_h + rsh + ty * roi_h;
    const float wst = (float)pw * bin_w + rsw + tx * roi_w;
    float wh[6] = {0, 0, 0, 0, 0, 0};
    float hc0 = fminf(fmaxf(hst, 0.0f), 99.0f);
    const int r0 = (int)hc0;
    int rtop = r0;
    float vsh = 0.0f;
#pragma unroll
    for (int i = 0; i < 4; i++) {
      float h = hst + (float)i * sub_h;
      bool v = (h >= -0.5f) && (h <= (float)HH - 0.5f);
      float hc = fminf(fmaxf(h, 0.0f), 99.0f);
      int h0 = (int)hc;
      float lh = hc - (float)h0;
      int h1 = min(h0 + 1, HH - 1);
      if (v) { wh[h0 - r0] += 1.0f - lh; wh[h1 - r0] += lh; vsh += 1.0f; }
      rtop = h1;
    }
    float wwc[6] = {0, 0, 0, 0, 0, 0};
    float wc0 = fminf(fmaxf(wst, 0.0f), 99.0f);
    const int c0 = (int)wc0;
    int ctop = c0;
    float vsw = 0.0f;
#pragma unroll
    for (int j = 0; j < 4; j++) {
      float w = wst + (float)j * sub_w;
      bool v = (w >= -0.5f) && (w <= (float)WW - 0.5f);
      float wc = fminf(fmaxf(w, 0.0f), 99.0f);
      int w0 = (int)wc;
      float lw = wc - (float)w0;
      int w1 = min(w0 + 1, WW - 1);
      if (v) { wwc[w0 - c0] += 1.0f - lw; wwc[w1 - c0] += lw; vsw += 1.0f; }
      ctop = w1;
    }
    const int nr = rtop - r0 + 1, nc = ctop - c0 + 1;
    float cntf = vsh * vsw;
    s_scale[p] = (cntf > 0.0f) ? mask / cntf : 0.0f;
    PixW* dst = &s_pix[p * 28];
    int m = 0;
    for (int ri = 0; ri < nr; ri++) {
      int rowoff = (r0 + ri) * WW + c0;
      for (int ci = 0; ci < nc; ci++) {
        dst[m].idx = (rowoff + ci) * CC;
        dst[m].w = wh[ri] * wwc[ci];
        m++;
      }
    }
    while (m & 3) { dst[m].idx = 0; dst[m].w = 0.0f; m++; }
    s_cnt[p] = m;
  }
  __syncthreads();

  const int wv = tid >> 6;
  const int c4 = (tid & 63) * 4;
  for (int p = wv; p < 49; p += 8) {
    const int cnt = __builtin_amdgcn_readfirstlane(s_cnt[p]);
    const PixW* cp = &s_pix[p * 28];
    float a0 = 0.0f, a1 = 0.0f, a2 = 0.0f, a3 = 0.0f;
    for (int q = 0; q < cnt; q += 4) {
#pragma unroll
      for (int u = 0; u < 4; u++) {
        PixW e = cp[q + u];
        int si = __builtin_amdgcn_readfirstlane(e.idx);
        float sw = __uint_as_float(__builtin_amdgcn_readfirstlane(__float_as_uint(e.w)));
        f16x4 v = *(const f16x4*)(fb + si + c4);
        a0 += sw * (float)v[0];
        a1 += sw * (float)v[1];
        a2 += sw * (float)v[2];
        a3 += sw * (float)v[3];
      }
    }
    float sc = s_scale[p];
    a0 *= sc; a1 *= sc; a2 *= sc; a3 *= sc;
    if (PASS2) {
      s_outf[(c4 + 0) * 49 + p] = a0;
      s_outf[(c4 + 1) * 49 + p] = a1;
      s_outf[(c4 + 2) * 49 + p] = a2;
      s_outf[(c4 + 3) * 49 + p] = a3;
    } else {
      s_outh[(c4 + 0) * 49 + p] = (half_t)a0;
      s_outh[(c4 + 1) * 49 + p] = (half_t)a1;
      s_outh[(c4 + 2) * 49 + p] = (half_t)a2;
      s_outh[(c4 + 3) * 49 + p] = (half_t)a3;
    }
  }
  __syncthreads();

  if (PASS2) {
    float* ob = out + (size_t)n * KDIM;
    for (int l = tid * 4; l < KDIM; l += 2048)
      *(float4*)(ob + l) = *(const float4*)(s_outf + l);
  } else {
    half_t* ob = xout + (size_t)n * KDIM;
    for (int l = tid * 8; l < KDIM; l += 4096)
      *(f16x8*)(ob + l) = *(const f16x8*)(s_outh + l);
  }
}

// ---- split-K fp16 MFMA GEMM, 1-barrier pipelined (T3/T4): 128x128 tile, BK=64 ----
// 256 thr / 4 waves, double-buffered LDS (64 KB -> 2 blocks/CU). Register-staged
// global loads issued at iter t, ds_written at iter t+1: loads span the raw
// s_barrier (vmcnt NOT drained; only lgkmcnt(0) per wave). This removes the
// compiler's full vmcnt(0)+lgkmcnt(0) drain that __syncthreads emits twice per
// K-step -- the latency-bound stall diagnosed at MfmaUtil 7.6%/HBM 17%.
// Hazard proof: each wave drains its own LDS reads+writes (lgkmcnt(0)) before
// every barrier; iter t writes buf[nxt], last read before the iter t-1 barrier.
// XCD swizzle: per-XCD contiguous g range (4*SK blocks/XCD), z-major -> per-z
// A+B slices stay in that XCD's L2.
// P layout: [z][tile=by*4+bx][wave][q=(i*4+j)*4+rr][lane]
template <int SK>
__global__ __launch_bounds__(256, 2) void gemm_pipe(const half_t* __restrict__ A,
                                                    const half_t* __restrict__ B,
                                                    float* __restrict__ P, int K) {
  __shared__ half_t As[2][128 * 64];   // 32 KB
  __shared__ half_t Bs[2][128 * 64];   // 32 KB
  const int d = blockIdx.x + gridDim.x * (blockIdx.y + gridDim.y * blockIdx.z);
  const int g = (d & 7) * (SK * 4) + (d >> 3);   // bijective: 32*SK blocks, %8==0
  const int z = g >> 5;          // 32 tiles per z-slice
  const int tile = g & 31;
  const int m0 = (tile & 3) * 128;
  const int n0 = (tile >> 2) * 128;
  const int Kc = K / SK;
  const int kbeg = z * Kc;
  const int tid = threadIdx.x;
  const int lane = tid & 63;
  const int wave = tid >> 6;
  const int wm = (wave & 1) * 64;
  const int wn = (wave >> 1) * 64;
  const int r = tid >> 3;                 // 0..31 staging row
  const int cg = tid & 7;                 // linear global chunk (16B)
  const int csw = (cg ^ (r & 7)) * 8;     // swizzled LDS chunk offset (halfs)
  const int fr = lane & 15;
  const int kc0 = lane >> 4;              // 0..3
  f32x4 acc[4][4] = {};
  const half_t* Ap = A + (size_t)(m0 + r) * K + kbeg + cg * 8;
  const half_t* Bp = B + (size_t)(n0 + r) * K + kbeg + cg * 8;
  uint4 ra[4], rb[4];
  const int iters = Kc >> 6;
  // prologue: tile0 -> regs -> LDS buf0; tile1 -> regs (in flight across barrier)
#pragma unroll
  for (int s = 0; s < 4; s++) ra[s] = *(const uint4*)(Ap + (size_t)(32 * s) * K);
#pragma unroll
  for (int s = 0; s < 4; s++) rb[s] = *(const uint4*)(Bp + (size_t)(32 * s) * K);
#pragma unroll
  for (int s = 0; s < 4; s++) *(uint4*)&As[0][(r + 32 * s) * 64 + csw] = ra[s];
#pragma unroll
  for (int s = 0; s < 4; s++) *(uint4*)&Bs[0][(r + 32 * s) * 64 + csw] = rb[s];
  if (iters > 1) {
#pragma unroll
    for (int s = 0; s < 4; s++) ra[s] = *(const uint4*)(Ap + (size_t)(32 * s) * K + 64);
#pragma unroll
    for (int s = 0; s < 4; s++) rb[s] = *(const uint4*)(Bp + (size_t)(32 * s) * K + 64);
  }
  asm volatile("s_waitcnt lgkmcnt(0)" ::: "memory");
  __builtin_amdgcn_s_barrier();
  for (int it = 0; it < iters; it++) {
    const int cur = it & 1;
#pragma unroll
    for (int ks = 0; ks < 2; ks++) {
      const int swz = ((kc0 + ks * 4) ^ (fr & 7)) * 8;
      f16x8 af[4], bf[4];
#pragma unroll
      for (int i = 0; i < 4; i++) af[i] = *(const f16x8*)&As[cur][(wm + i * 16 + fr) * 64 + swz];
#pragma unroll
      for (int j = 0; j < 4; j++) bf[j] = *(const f16x8*)&Bs[cur][(wn + j * 16 + fr) * 64 + swz];
#pragma unroll
      for (int i = 0; i < 4; i++)
#pragma unroll
        for (int j = 0; j < 4; j++)
          acc[i][j] = __builtin_amdgcn_mfma_f32_16x16x32_f16(af[i], bf[j], acc[i][j], 0, 0, 0);
    }
    if (it + 1 < iters) {
      const int nxt = cur ^ 1;
      // ds_write tile t+1 from regs (auto counted-vmcnt wait; loads had a full
      // compute phase to land), then issue tile t+2 loads into the freed regs.
#pragma unroll
      for (int s = 0; s < 4; s++) *(uint4*)&As[nxt][(r + 32 * s) * 64 + csw] = ra[s];
#pragma unroll
      for (int s = 0; s < 4; s++) *(uint4*)&Bs[nxt][(r + 32 * s) * 64 + csw] = rb[s];
      if (it + 2 < iters) {
        const int ko = (it + 2) * 64;
#pragma unroll
        for (int s = 0; s < 4; s++) ra[s] = *(const uint4*)(Ap + (size_t)(32 * s) * K + ko);
#pragma unroll
        for (int s = 0; s < 4; s++) rb[s] = *(const uint4*)(Bp + (size_t)(32 * s) * K + ko);
      }
    }
    asm volatile("s_waitcnt lgkmcnt(0)" ::: "memory");
    __builtin_amdgcn_s_barrier();
  }
  // blocked store: 256B contiguous per (q) store
  float* Pz = P + (((size_t)z * 32 + tile) * 4 + wave) * 4096;
#pragma unroll
  for (int i = 0; i < 4; i++)
#pragma unroll
    for (int j = 0; j < 4; j++)
#pragma unroll
      for (int rr = 0; rr < 4; rr++)
        Pz[((i * 4 + j) * 4 + rr) * 64 + lane] = acc[i][j][rr];
}

// ---- reduce SK blocked partials + bias (+relu), write fp16 or fp32 (128x128 layout) ----
template <bool OUT16, bool RELU, int SK>
__global__ __launch_bounds__(256) void reduce_blocked(const float* __restrict__ P,
                                                      const float* __restrict__ bias,
                                                      void* __restrict__ out,
                                                      int MN, int N) {
  int i4 = (blockIdx.x * 256 + threadIdx.x) * 4;
  if (i4 >= MN) return;
  float4 s = *(const float4*)(P + i4);
#pragma unroll
  for (int z = 1; z < SK; z++) {
    float4 t = *(const float4*)(P + (size_t)z * MN + i4);
    s.x += t.x; s.y += t.y; s.z += t.z; s.w += t.w;
  }
  const int lane0 = i4 & 63;
  const int q     = (i4 >> 6) & 63;
  const int wave  = (i4 >> 12) & 3;
  const int bx    = (i4 >> 14) & 3;
  const int by    = (i4 >> 16) & 7;
  const int rr = q & 3, j_ = (q >> 2) & 3, i_ = q >> 4;
  const int row = bx * 128 + (wave & 1) * 64 + i_ * 16 + (lane0 >> 4) * 4 + rr;
  const int col = by * 128 + (wave >> 1) * 64 + j_ * 16 + (lane0 & 15);
  float4 bv = *(const float4*)(bias + col);
  s.x += bv.x; s.y += bv.y; s.z += bv.z; s.w += bv.w;
  if (RELU) {
    s.x = fmaxf(s.x, 0.0f); s.y = fmaxf(s.y, 0.0f);
    s.z = fmaxf(s.z, 0.0f); s.w = fmaxf(s.w, 0.0f);
  }
  size_t o = (size_t)row * N + col;
  if (OUT16) {
    f16x4 ov;
    ov[0] = (half_t)s.x; ov[1] = (half_t)s.y; ov[2] = (half_t)s.z; ov[3] = (half_t)s.w;
    *(f16x4*)((half_t*)out + o) = ov;
  } else {
    *(float4*)((float*)out + o) = s;
  }
}

// ---------------- fp32 GEMM3: om(N,147) = h2(N,1024) @ w3(147,1024)^T + b3 ----------------
__global__ __launch_bounds__(192) void gemm_small(const float* __restrict__ h2,
                                                  const float* __restrict__ w3,
                                                  const float* __restrict__ b3,
                                                  float* __restrict__ om) {
  __shared__ float hs[FC];
  int n = blockIdx.x;
  for (int k = threadIdx.x; k < FC; k += 192) hs[k] = h2[(size_t)n * FC + k];
  __syncthreads();
  int j = threadIdx.x;
  if (j < 147) {
    float acc = b3[j];
    const float* wr = w3 + (size_t)j * FC;
    for (int k = 0; k < FC; k += 4) {
      float4 wv = *(const float4*)(wr + k);
      acc += hs[k] * wv.x + hs[k + 1] * wv.y + hs[k + 2] * wv.z + hs[k + 3] * wv.w;
    }
    om[n * 147 + j] = acc;
  }
}

extern "C" void kernel_launch(void* const* d_in, const int* in_sizes, int n_in,
                              void* d_out, int out_size, void* d_ws, size_t ws_size,
                              hipStream_t stream) {
  const float* feat = (const float*)d_in[0];
  const float* rois = (const float*)d_in[1];
  const float* w1 = (const float*)d_in[2];
  const float* b1 = (const float*)d_in[3];
  const float* w2 = (const float*)d_in[4];
  const float* b2 = (const float*)d_in[5];
  const float* w3 = (const float*)d_in[6];
  const float* b3 = (const float*)d_in[7];
  float* out = (float*)d_out;
  char* ws = (char*)d_ws;

  // workspace carve (~83.7 MB total)
  half_t* featT = (half_t*)ws;                        // 10,240,000 B
  half_t* xh    = (half_t*)(ws + 10240000);           // 12,845,056 B  (k = c*49+p)
  half_t* w1h   = (half_t*)(ws + 23085056);           // 25,690,112 B  (raw layout)
  half_t* w2h   = (half_t*)(ws + 48775168);           //  2,097,152 B
  half_t* h1    = (half_t*)(ws + 50872320);           //  1,048,576 B
  float*  h2    = (float*)(ws + 51920896);            //  2,097,152 B
  float*  omb   = (float*)(ws + 54018048);            //    301,056 B
  float*  part  = (float*)(ws + 54319104);            // 29,360,128 B

  const int MN = NROI * FC;  // 524288

  transpose_feat<<<dim3(313, 8, 2), dim3(32, 8), 0, stream>>>(feat, featT);
  convert_f32_f16<<<dim3(12544), dim3(256), 0, stream>>>(w1, w1h, FC * KDIM);
  convert_f32_f16<<<dim3(1024), dim3(256), 0, stream>>>(w2, w2h, FC * FC);
  pool_kernel<false><<<dim3(NROI), dim3(512), 0, stream>>>(featT, rois, nullptr, xh, nullptr);

  // GEMM1: (512x12544) @ (1024x12544)^T -> 128x128 tiles, SK=14, 448 blocks, XCD-swizzled
  gemm_pipe<14><<<dim3(4, 8, 14), dim3(256), 0, stream>>>(xh, w1h, part, KDIM);
  reduce_blocked<true, true, 14><<<dim3(MN / 1024), dim3(256), 0, stream>>>(part, b1, (void*)h1, MN, FC);

  // GEMM2: (512x1024) @ (1024x1024)^T -> SK=8, 256 blocks, XCD-swizzled
  gemm_pipe<8><<<dim3(4, 8, 8), dim3(256), 0, stream>>>(h1, w2h, part, FC);
  reduce_blocked<false, true, 8><<<dim3(MN / 1024), dim3(256), 0, stream>>>(part, b2, (void*)h2, MN, FC);

  gemm_small<<<dim3(NROI), dim3(192), 0, stream>>>(h2, w3, b3, omb);
  pool_kernel<true><<<dim3(NROI), dim3(512), 0, stream>>>(featT, rois, omb, nullptr, out);
}

// Round 3
// 255.360 us; speedup vs baseline: 1.1671x; 1.1671x over previous
//
#include <hip/hip_runtime.h>

// Problem constants (fixed by setup_inputs)
#define BB 2
#define CC 256
#define HH 100
#define WW 100
#define NROI 512
#define KDIM 12544   // 49*256
#define FC 1024

typedef _Float16 half_t;
typedef _Float16 f16x2 __attribute__((ext_vector_type(2)));
typedef _Float16 f16x8 __attribute__((ext_vector_type(8)));
typedef _Float16 f16x4 __attribute__((ext_vector_type(4)));
typedef float f32x4 __attribute__((ext_vector_type(4)));

// async global->LDS DMA, 16B per lane, wave-uniform LDS base + lane*16
__device__ __forceinline__ void gload16(const half_t* g, half_t* l) {
  __builtin_amdgcn_global_load_lds(
      (const __attribute__((address_space(1))) unsigned int*)g,
      (__attribute__((address_space(3))) unsigned int*)l, 16, 0, 0);
}

// ---------------- feat (B,C,H,W) fp32 -> featT (B,H*W,C) fp16 ----------------
__global__ __launch_bounds__(256) void transpose_feat(const float* __restrict__ feat,
                                                      half_t* __restrict__ featT) {
  __shared__ float tile[32][33];
  int b = blockIdx.z;
  int hw0 = blockIdx.x * 32;
  int c0 = blockIdx.y * 32;
  int tx = threadIdx.x, ty = threadIdx.y;
  const float* fb = feat + (size_t)b * CC * (HH * WW);
#pragma unroll
  for (int i = 0; i < 4; i++) {
    int c = c0 + ty + i * 8;
    int hw = hw0 + tx;
    tile[ty + i * 8][tx] = (hw < HH * WW) ? fb[(size_t)c * (HH * WW) + hw] : 0.0f;
  }
  __syncthreads();
  half_t* ob = featT + (size_t)b * (HH * WW) * CC;
#pragma unroll
  for (int i = 0; i < 4; i++) {
    int hw = hw0 + ty + i * 8;
    int c = c0 + tx;
    if (hw < HH * WW) ob[(size_t)hw * CC + c] = (half_t)tile[tx][ty + i * 8];
  }
}

// ---------------- fp32 -> fp16 convert (w1, w2) ----------------
__global__ __launch_bounds__(256) void convert_f32_f16(const float* __restrict__ in,
                                                       half_t* __restrict__ out, int n) {
  int i4 = (blockIdx.x * 256 + threadIdx.x) * 4;
  if (i4 < n) {
    float4 v = *(const float4*)(in + i4);
    f16x4 o;
    o[0] = (half_t)v.x; o[1] = (half_t)v.y; o[2] = (half_t)v.z; o[3] = (half_t)v.w;
    *(f16x4*)(out + i4) = o;
  }
}

// ---------------- deformable PSROI pooling, one block (512 thr) per ROI ----------------
struct PixW { int idx; float w; };

template <bool PASS2>
__global__ __launch_bounds__(512) void pool_kernel(const half_t* __restrict__ featT,
                                                   const float* __restrict__ rois,
                                                   const float* __restrict__ om,
                                                   half_t* __restrict__ xout,
                                                   float* __restrict__ out) {
  __shared__ PixW s_pix[49 * 28];
  __shared__ int s_cnt[49];
  __shared__ float s_scale[49];
  __shared__ float  s_outf[PASS2 ? KDIM : 1];
  __shared__ half_t s_outh[PASS2 ? 1 : KDIM];

  const int n = blockIdx.x;
  const int tid = threadIdx.x;
  const float* r = rois + n * 5;
  const int b = (int)r[0];
  const float rsw = rintf(r[1]) * 0.0625f - 0.5f;
  const float rsh = rintf(r[2]) * 0.0625f - 0.5f;
  const float rew = (rintf(r[3]) + 1.0f) * 0.0625f - 0.5f;
  const float reh = (rintf(r[4]) + 1.0f) * 0.0625f - 0.5f;
  const float roi_w = fmaxf(rew - rsw, 0.1f);
  const float roi_h = fmaxf(reh - rsh, 0.1f);
  const float bin_h = roi_h / 7.0f, bin_w = roi_w / 7.0f;
  const float sub_h = bin_h * 0.25f, sub_w = bin_w * 0.25f;
  const half_t* fb = featT + (size_t)b * (HH * WW) * CC;

  if (tid < 49) {
    const int p = tid, ph = p / 7, pw = p - ph * 7;
    float tx = 0.0f, ty = 0.0f, mask = 1.0f;
    if (PASS2) {
      tx = om[n * 147 + p] * 0.1f;
      ty = om[n * 147 + 49 + p] * 0.1f;
      mask = 1.0f / (1.0f + expf(-om[n * 147 + 98 + p]));
    }
    const float hst = (float)ph * bin_h + rsh + ty * roi_h;
    const float wst = (float)pw * bin_w + rsw + tx * roi_w;
    float wh[6] = {0, 0, 0, 0, 0, 0};
    float hc0 = fminf(fmaxf(hst, 0.0f), 99.0f);
    const int r0 = (int)hc0;
    int rtop = r0;
    float vsh = 0.0f;
#pragma unroll
    for (int i = 0; i < 4; i++) {
      float h = hst + (float)i * sub_h;
      bool v = (h >= -0.5f) && (h <= (float)HH - 0.5f);
      float hc = fminf(fmaxf(h, 0.0f), 99.0f);
      int h0 = (int)hc;
      float lh = hc - (float)h0;
      int h1 = min(h0 + 1, HH - 1);
      if (v) { wh[h0 - r0] += 1.0f - lh; wh[h1 - r0] += lh; vsh += 1.0f; }
      rtop = h1;
    }
    float wwc[6] = {0, 0, 0, 0, 0, 0};
    float wc0 = fminf(fmaxf(wst, 0.0f), 99.0f);
    const int c0 = (int)wc0;
    int ctop = c0;
    float vsw = 0.0f;
#pragma unroll
    for (int j = 0; j < 4; j++) {
      float w = wst + (float)j * sub_w;
      bool v = (w >= -0.5f) && (w <= (float)WW - 0.5f);
      float wc = fminf(fmaxf(w, 0.0f), 99.0f);
      int w0 = (int)wc;
      float lw = wc - (float)w0;
      int w1 = min(w0 + 1, WW - 1);
      if (v) { wwc[w0 - c0] += 1.0f - lw; wwc[w1 - c0] += lw; vsw += 1.0f; }
      ctop = w1;
    }
    const int nr = rtop - r0 + 1, nc = ctop - c0 + 1;
    float cntf = vsh * vsw;
    s_scale[p] = (cntf > 0.0f) ? mask / cntf : 0.0f;
    PixW* dst = &s_pix[p * 28];
    int m = 0;
    for (int ri = 0; ri < nr; ri++) {
      int rowoff = (r0 + ri) * WW + c0;
      for (int ci = 0; ci < nc; ci++) {
        dst[m].idx = (rowoff + ci) * CC;
        dst[m].w = wh[ri] * wwc[ci];
        m++;
      }
    }
    while (m & 3) { dst[m].idx = 0; dst[m].w = 0.0f; m++; }
    s_cnt[p] = m;
  }
  __syncthreads();

  const int wv = tid >> 6;
  const int c4 = (tid & 63) * 4;
  for (int p = wv; p < 49; p += 8) {
    const int cnt = __builtin_amdgcn_readfirstlane(s_cnt[p]);
    const PixW* cp = &s_pix[p * 28];
    float a0 = 0.0f, a1 = 0.0f, a2 = 0.0f, a3 = 0.0f;
    for (int q = 0; q < cnt; q += 4) {
#pragma unroll
      for (int u = 0; u < 4; u++) {
        PixW e = cp[q + u];
        int si = __builtin_amdgcn_readfirstlane(e.idx);
        float sw = __uint_as_float(__builtin_amdgcn_readfirstlane(__float_as_uint(e.w)));
        f16x4 v = *(const f16x4*)(fb + si + c4);
        a0 += sw * (float)v[0];
        a1 += sw * (float)v[1];
        a2 += sw * (float)v[2];
        a3 += sw * (float)v[3];
      }
    }
    float sc = s_scale[p];
    a0 *= sc; a1 *= sc; a2 *= sc; a3 *= sc;
    if (PASS2) {
      s_outf[(c4 + 0) * 49 + p] = a0;
      s_outf[(c4 + 1) * 49 + p] = a1;
      s_outf[(c4 + 2) * 49 + p] = a2;
      s_outf[(c4 + 3) * 49 + p] = a3;
    } else {
      s_outh[(c4 + 0) * 49 + p] = (half_t)a0;
      s_outh[(c4 + 1) * 49 + p] = (half_t)a1;
      s_outh[(c4 + 2) * 49 + p] = (half_t)a2;
      s_outh[(c4 + 3) * 49 + p] = (half_t)a3;
    }
  }
  __syncthreads();

  if (PASS2) {
    float* ob = out + (size_t)n * KDIM;
    for (int l = tid * 4; l < KDIM; l += 2048)
      *(float4*)(ob + l) = *(const float4*)(s_outf + l);
  } else {
    half_t* ob = xout + (size_t)n * KDIM;
    for (int l = tid * 8; l < KDIM; l += 4096)
      *(f16x8*)(ob + l) = *(const f16x8*)(s_outh + l);
  }
}

// ---- split-K fp16 MFMA GEMM, global_load_lds + counted vmcnt (T3/T4) ----
// 128x128 tile, BK=64, 256 thr / 4 waves, double-buffered LDS (64 KB, 2 blocks/CU).
// Staging: 8 global_load_lds DMAs per wave per K-step (4 A + 4 B, 1 KB each),
// LDS dest linear (wave-uniform base + lane*16). Bank swizzle applied on the
// GLOBAL SOURCE side: lane l loads chunk (l&7)^(l>>3) of its row, so LDS phys
// chunk p of row r holds global chunk p^(r&7); ds_read XORs it back. Read is
// 2 lanes/bank (free); DMA write is 1KB contiguous (conflict-free).
// Waits: counted vmcnt(8) (older tile's 8 DMAs) before a raw s_barrier; the 8
// just-issued DMAs stay in flight across the barrier -- no vmcnt(0) in loop.
// Hazards: lgkmcnt(0)+barrier after MFMA ensures all waves' reads of buf[cur]
// done before re-staging it; vmcnt(N)+barrier ensures buf for next iter complete.
// XCD swizzle: per-XCD contiguous g range, z-major -> A/B K-slices stay in L2.
// P layout: [z][tile=by*4+bx][wave][q=(i*4+j)*4+rr][lane]
template <int SK>
__global__ __launch_bounds__(256, 2) void gemm_lds(const half_t* __restrict__ A,
                                                   const half_t* __restrict__ B,
                                                   float* __restrict__ P, int K) {
  __shared__ half_t As[2][128 * 64];   // 32 KB
  __shared__ half_t Bs[2][128 * 64];   // 32 KB
  const int d = blockIdx.x + gridDim.x * (blockIdx.y + gridDim.y * blockIdx.z);
  const int g = (d & 7) * (SK * 4) + (d >> 3);   // bijective: 32*SK blocks, %8==0
  const int z = g >> 5;          // 32 tiles per z-slice
  const int tile = g & 31;
  const int m0 = (tile & 3) * 128;
  const int n0 = (tile >> 2) * 128;
  const int Kc = K / SK;
  const int kbeg = z * Kc;
  const int tid = threadIdx.x;
  const int lane = tid & 63;
  const int wave = tid >> 6;
  const int wm = (wave & 1) * 64;
  const int wn = (wave >> 1) * 64;
  const int fr = lane & 15;
  const int kc0 = lane >> 4;              // 0..3
  // staging geometry: call s covers rows s*32 + wave*8 + (lane>>3)
  const int lr = lane >> 3;               // 0..7
  const int lc = (lane & 7) ^ lr;         // pre-swizzled global 16B-chunk
  const half_t* Ag = A + (size_t)(m0 + wave * 8 + lr) * K + kbeg + lc * 8;
  const half_t* Bg = B + (size_t)(n0 + wave * 8 + lr) * K + kbeg + lc * 8;
  f32x4 acc[4][4] = {};

  auto stage = [&](int buf, int ko) {
#pragma unroll
    for (int s = 0; s < 4; s++)
      gload16(Ag + (size_t)(32 * s) * K + ko, &As[buf][s * 2048 + wave * 512]);
#pragma unroll
    for (int s = 0; s < 4; s++)
      gload16(Bg + (size_t)(32 * s) * K + ko, &Bs[buf][s * 2048 + wave * 512]);
  };

  const int iters = Kc >> 6;
  // prologue: tile0 -> buf0; tile1 -> buf1 (stays in flight across barrier)
  stage(0, 0);
  if (iters > 1) {
    stage(1, 64);
    asm volatile("s_waitcnt vmcnt(8)" ::: "memory");   // buf0 complete, buf1 in flight
  } else {
    asm volatile("s_waitcnt vmcnt(0)" ::: "memory");
  }
  __builtin_amdgcn_s_barrier();

  for (int it = 0; it < iters; it++) {
    const int cur = it & 1;
#pragma unroll
    for (int ks = 0; ks < 2; ks++) {
      const int swz = ((kc0 + ks * 4) ^ (fr & 7)) * 8;
      f16x8 af[4], bf[4];
#pragma unroll
      for (int i = 0; i < 4; i++) af[i] = *(const f16x8*)&As[cur][(wm + i * 16 + fr) * 64 + swz];
#pragma unroll
      for (int j = 0; j < 4; j++) bf[j] = *(const f16x8*)&Bs[cur][(wn + j * 16 + fr) * 64 + swz];
#pragma unroll
      for (int i = 0; i < 4; i++)
#pragma unroll
        for (int j = 0; j < 4; j++)
          acc[i][j] = __builtin_amdgcn_mfma_f32_16x16x32_f16(af[i], bf[j], acc[i][j], 0, 0, 0);
    }
    // all my LDS reads done; all waves' reads done -> safe to re-stage buf[cur]
    asm volatile("s_waitcnt lgkmcnt(0)" ::: "memory");
    __builtin_amdgcn_s_barrier();
    const bool issue = (it + 2 < iters);
    if (issue) stage(cur, (it + 2) * 64);
    if (it + 1 < iters) {
      if (issue) asm volatile("s_waitcnt vmcnt(8)" ::: "memory");  // older batch only
      else       asm volatile("s_waitcnt vmcnt(0)" ::: "memory");  // nothing newer in flight
      __builtin_amdgcn_s_barrier();
    }
  }
  // blocked store: 256B contiguous per (q) store
  float* Pz = P + (((size_t)z * 32 + tile) * 4 + wave) * 4096;
#pragma unroll
  for (int i = 0; i < 4; i++)
#pragma unroll
    for (int j = 0; j < 4; j++)
#pragma unroll
      for (int rr = 0; rr < 4; rr++)
        Pz[((i * 4 + j) * 4 + rr) * 64 + lane] = acc[i][j][rr];
}

// ---- reduce SK blocked partials + bias (+relu), write fp16 or fp32 (128x128 layout) ----
template <bool OUT16, bool RELU, int SK>
__global__ __launch_bounds__(256) void reduce_blocked(const float* __restrict__ P,
                                                      const float* __restrict__ bias,
                                                      void* __restrict__ out,
                                                      int MN, int N) {
  int i4 = (blockIdx.x * 256 + threadIdx.x) * 4;
  if (i4 >= MN) return;
  float4 s = *(const float4*)(P + i4);
#pragma unroll
  for (int z = 1; z < SK; z++) {
    float4 t = *(const float4*)(P + (size_t)z * MN + i4);
    s.x += t.x; s.y += t.y; s.z += t.z; s.w += t.w;
  }
  const int lane0 = i4 & 63;
  const int q     = (i4 >> 6) & 63;
  const int wave  = (i4 >> 12) & 3;
  const int bx    = (i4 >> 14) & 3;
  const int by    = (i4 >> 16) & 7;
  const int rr = q & 3, j_ = (q >> 2) & 3, i_ = q >> 4;
  const int row = bx * 128 + (wave & 1) * 64 + i_ * 16 + (lane0 >> 4) * 4 + rr;
  const int col = by * 128 + (wave >> 1) * 64 + j_ * 16 + (lane0 & 15);
  float4 bv = *(const float4*)(bias + col);
  s.x += bv.x; s.y += bv.y; s.z += bv.z; s.w += bv.w;
  if (RELU) {
    s.x = fmaxf(s.x, 0.0f); s.y = fmaxf(s.y, 0.0f);
    s.z = fmaxf(s.z, 0.0f); s.w = fmaxf(s.w, 0.0f);
  }
  size_t o = (size_t)row * N + col;
  if (OUT16) {
    f16x4 ov;
    ov[0] = (half_t)s.x; ov[1] = (half_t)s.y; ov[2] = (half_t)s.z; ov[3] = (half_t)s.w;
    *(f16x4*)((half_t*)out + o) = ov;
  } else {
    *(float4*)((float*)out + o) = s;
  }
}

// ---------------- fp32 GEMM3: om(N,147) = h2(N,1024) @ w3(147,1024)^T + b3 ----------------
__global__ __launch_bounds__(192) void gemm_small(const float* __restrict__ h2,
                                                  const float* __restrict__ w3,
                                                  const float* __restrict__ b3,
                                                  float* __restrict__ om) {
  __shared__ float hs[FC];
  int n = blockIdx.x;
  for (int k = threadIdx.x; k < FC; k += 192) hs[k] = h2[(size_t)n * FC + k];
  __syncthreads();
  int j = threadIdx.x;
  if (j < 147) {
    float acc = b3[j];
    const float* wr = w3 + (size_t)j * FC;
    for (int k = 0; k < FC; k += 4) {
      float4 wv = *(const float4*)(wr + k);
      acc += hs[k] * wv.x + hs[k + 1] * wv.y + hs[k + 2] * wv.z + hs[k + 3] * wv.w;
    }
    om[n * 147 + j] = acc;
  }
}

extern "C" void kernel_launch(void* const* d_in, const int* in_sizes, int n_in,
                              void* d_out, int out_size, void* d_ws, size_t ws_size,
                              hipStream_t stream) {
  const float* feat = (const float*)d_in[0];
  const float* rois = (const float*)d_in[1];
  const float* w1 = (const float*)d_in[2];
  const float* b1 = (const float*)d_in[3];
  const float* w2 = (const float*)d_in[4];
  const float* b2 = (const float*)d_in[5];
  const float* w3 = (const float*)d_in[6];
  const float* b3 = (const float*)d_in[7];
  float* out = (float*)d_out;
  char* ws = (char*)d_ws;

  // workspace carve (~83.7 MB total)
  half_t* featT = (half_t*)ws;                        // 10,240,000 B
  half_t* xh    = (half_t*)(ws + 10240000);           // 12,845,056 B  (k = c*49+p)
  half_t* w1h   = (half_t*)(ws + 23085056);           // 25,690,112 B  (raw layout)
  half_t* w2h   = (half_t*)(ws + 48775168);           //  2,097,152 B
  half_t* h1    = (half_t*)(ws + 50872320);           //  1,048,576 B
  float*  h2    = (float*)(ws + 51920896);            //  2,097,152 B
  float*  omb   = (float*)(ws + 54018048);            //    301,056 B
  float*  part  = (float*)(ws + 54319104);            // 29,360,128 B

  const int MN = NROI * FC;  // 524288

  transpose_feat<<<dim3(313, 8, 2), dim3(32, 8), 0, stream>>>(feat, featT);
  convert_f32_f16<<<dim3(12544), dim3(256), 0, stream>>>(w1, w1h, FC * KDIM);
  convert_f32_f16<<<dim3(1024), dim3(256), 0, stream>>>(w2, w2h, FC * FC);
  pool_kernel<false><<<dim3(NROI), dim3(512), 0, stream>>>(featT, rois, nullptr, xh, nullptr);

  // GEMM1: (512x12544) @ (1024x12544)^T -> 128x128 tiles, SK=14, 448 blocks, XCD-swizzled
  gemm_lds<14><<<dim3(4, 8, 14), dim3(256), 0, stream>>>(xh, w1h, part, KDIM);
  reduce_blocked<true, true, 14><<<dim3(MN / 1024), dim3(256), 0, stream>>>(part, b1, (void*)h1, MN, FC);

  // GEMM2: (512x1024) @ (1024x1024)^T -> SK=8, 256 blocks, XCD-swizzled
  gemm_lds<8><<<dim3(4, 8, 8), dim3(256), 0, stream>>>(h1, w2h, part, FC);
  reduce_blocked<false, true, 8><<<dim3(MN / 1024), dim3(256), 0, stream>>>(part, b2, (void*)h2, MN, FC);

  gemm_small<<<dim3(NROI), dim3(192), 0, stream>>>(h2, w3, b3, omb);
  pool_kernel<true><<<dim3(NROI), dim3(512), 0, stream>>>(featT, rois, omb, nullptr, out);
}

// Round 4
// 229.371 us; speedup vs baseline: 1.2994x; 1.1133x over previous
//
#include <hip/hip_runtime.h>

// Problem constants (fixed by setup_inputs)
#define BB 2
#define CC 256
#define HH 100
#define WW 100
#define NROI 512
#define KDIM 12544   // 49*256
#define FC 1024

typedef _Float16 half_t;
typedef _Float16 f16x2 __attribute__((ext_vector_type(2)));
typedef _Float16 f16x8 __attribute__((ext_vector_type(8)));
typedef _Float16 f16x4 __attribute__((ext_vector_type(4)));
typedef float f32x4 __attribute__((ext_vector_type(4)));

// async global->LDS DMA, 16B per lane, wave-uniform LDS base + lane*16
__device__ __forceinline__ void gload16(const half_t* g, half_t* l) {
  __builtin_amdgcn_global_load_lds(
      (const __attribute__((address_space(1))) unsigned int*)g,
      (__attribute__((address_space(3))) unsigned int*)l, 16, 0, 0);
}

// ---------------- feat (B,C,H,W) fp32 -> featT (B,H*W,C) fp16 ----------------
__global__ __launch_bounds__(256) void transpose_feat(const float* __restrict__ feat,
                                                      half_t* __restrict__ featT) {
  __shared__ float tile[32][33];
  int b = blockIdx.z;
  int hw0 = blockIdx.x * 32;
  int c0 = blockIdx.y * 32;
  int tx = threadIdx.x, ty = threadIdx.y;
  const float* fb = feat + (size_t)b * CC * (HH * WW);
#pragma unroll
  for (int i = 0; i < 4; i++) {
    int c = c0 + ty + i * 8;
    int hw = hw0 + tx;
    tile[ty + i * 8][tx] = (hw < HH * WW) ? fb[(size_t)c * (HH * WW) + hw] : 0.0f;
  }
  __syncthreads();
  half_t* ob = featT + (size_t)b * (HH * WW) * CC;
#pragma unroll
  for (int i = 0; i < 4; i++) {
    int hw = hw0 + ty + i * 8;
    int c = c0 + tx;
    if (hw < HH * WW) ob[(size_t)hw * CC + c] = (half_t)tile[tx][ty + i * 8];
  }
}

// ---------------- fp32 -> fp16 convert (w1, w2) ----------------
__global__ __launch_bounds__(256) void convert_f32_f16(const float* __restrict__ in,
                                                       half_t* __restrict__ out, int n) {
  int i4 = (blockIdx.x * 256 + threadIdx.x) * 4;
  if (i4 < n) {
    float4 v = *(const float4*)(in + i4);
    f16x4 o;
    o[0] = (half_t)v.x; o[1] = (half_t)v.y; o[2] = (half_t)v.z; o[3] = (half_t)v.w;
    *(f16x4*)(out + i4) = o;
  }
}

// ---------------- deformable PSROI pooling, one block (512 thr) per ROI ----------------
// PASS2: om values come as split-K partials part3[z][n][147]; z-reduce + b3 bias
// folded into phase 1 (24 scalar loads by 49 threads, off the block critical path).
struct PixW { int idx; float w; };

template <bool PASS2>
__global__ __launch_bounds__(512) void pool_kernel(const half_t* __restrict__ featT,
                                                   const float* __restrict__ rois,
                                                   const float* __restrict__ part3,
                                                   const float* __restrict__ b3,
                                                   half_t* __restrict__ xout,
                                                   float* __restrict__ out) {
  __shared__ PixW s_pix[49 * 28];
  __shared__ int s_cnt[49];
  __shared__ float s_scale[49];
  __shared__ float  s_outf[PASS2 ? KDIM : 1];
  __shared__ half_t s_outh[PASS2 ? 1 : KDIM];

  const int n = blockIdx.x;
  const int tid = threadIdx.x;
  const float* r = rois + n * 5;
  const int b = (int)r[0];
  const float rsw = rintf(r[1]) * 0.0625f - 0.5f;
  const float rsh = rintf(r[2]) * 0.0625f - 0.5f;
  const float rew = (rintf(r[3]) + 1.0f) * 0.0625f - 0.5f;
  const float reh = (rintf(r[4]) + 1.0f) * 0.0625f - 0.5f;
  const float roi_w = fmaxf(rew - rsw, 0.1f);
  const float roi_h = fmaxf(reh - rsh, 0.1f);
  const float bin_h = roi_h / 7.0f, bin_w = roi_w / 7.0f;
  const float sub_h = bin_h * 0.25f, sub_w = bin_w * 0.25f;
  const half_t* fb = featT + (size_t)b * (HH * WW) * CC;

  if (tid < 49) {
    const int p = tid, ph = p / 7, pw = p - ph * 7;
    float tx = 0.0f, ty = 0.0f, mask = 1.0f;
    if (PASS2) {
      float o0 = b3[p], o1 = b3[49 + p], o2 = b3[98 + p];
#pragma unroll
      for (int zz = 0; zz < 8; zz++) {
        const float* pz = part3 + ((size_t)zz * NROI + n) * 147;
        o0 += pz[p]; o1 += pz[49 + p]; o2 += pz[98 + p];
      }
      tx = o0 * 0.1f;
      ty = o1 * 0.1f;
      mask = 1.0f / (1.0f + expf(-o2));
    }
    const float hst = (float)ph * bin_h + rsh + ty * roi_h;
    const float wst = (float)pw * bin_w + rsw + tx * roi_w;
    float wh[6] = {0, 0, 0, 0, 0, 0};
    float hc0 = fminf(fmaxf(hst, 0.0f), 99.0f);
    const int r0 = (int)hc0;
    int rtop = r0;
    float vsh = 0.0f;
#pragma unroll
    for (int i = 0; i < 4; i++) {
      float h = hst + (float)i * sub_h;
      bool v = (h >= -0.5f) && (h <= (float)HH - 0.5f);
      float hc = fminf(fmaxf(h, 0.0f), 99.0f);
      int h0 = (int)hc;
      float lh = hc - (float)h0;
      int h1 = min(h0 + 1, HH - 1);
      if (v) { wh[h0 - r0] += 1.0f - lh; wh[h1 - r0] += lh; vsh += 1.0f; }
      rtop = h1;
    }
    float wwc[6] = {0, 0, 0, 0, 0, 0};
    float wc0 = fminf(fmaxf(wst, 0.0f), 99.0f);
    const int c0 = (int)wc0;
    int ctop = c0;
    float vsw = 0.0f;
#pragma unroll
    for (int j = 0; j < 4; j++) {
      float w = wst + (float)j * sub_w;
      bool v = (w >= -0.5f) && (w <= (float)WW - 0.5f);
      float wc = fminf(fmaxf(w, 0.0f), 99.0f);
      int w0 = (int)wc;
      float lw = wc - (float)w0;
      int w1 = min(w0 + 1, WW - 1);
      if (v) { wwc[w0 - c0] += 1.0f - lw; wwc[w1 - c0] += lw; vsw += 1.0f; }
      ctop = w1;
    }
    const int nr = rtop - r0 + 1, nc = ctop - c0 + 1;
    float cntf = vsh * vsw;
    s_scale[p] = (cntf > 0.0f) ? mask / cntf : 0.0f;
    PixW* dst = &s_pix[p * 28];
    int m = 0;
    for (int ri = 0; ri < nr; ri++) {
      int rowoff = (r0 + ri) * WW + c0;
      for (int ci = 0; ci < nc; ci++) {
        dst[m].idx = (rowoff + ci) * CC;
        dst[m].w = wh[ri] * wwc[ci];
        m++;
      }
    }
    while (m & 3) { dst[m].idx = 0; dst[m].w = 0.0f; m++; }
    s_cnt[p] = m;
  }
  __syncthreads();

  const int wv = tid >> 6;
  const int c4 = (tid & 63) * 4;
  for (int p = wv; p < 49; p += 8) {
    const int cnt = __builtin_amdgcn_readfirstlane(s_cnt[p]);
    const PixW* cp = &s_pix[p * 28];
    float a0 = 0.0f, a1 = 0.0f, a2 = 0.0f, a3 = 0.0f;
    for (int q = 0; q < cnt; q += 4) {
#pragma unroll
      for (int u = 0; u < 4; u++) {
        PixW e = cp[q + u];
        int si = __builtin_amdgcn_readfirstlane(e.idx);
        float sw = __uint_as_float(__builtin_amdgcn_readfirstlane(__float_as_uint(e.w)));
        f16x4 v = *(const f16x4*)(fb + si + c4);
        a0 += sw * (float)v[0];
        a1 += sw * (float)v[1];
        a2 += sw * (float)v[2];
        a3 += sw * (float)v[3];
      }
    }
    float sc = s_scale[p];
    a0 *= sc; a1 *= sc; a2 *= sc; a3 *= sc;
    if (PASS2) {
      s_outf[(c4 + 0) * 49 + p] = a0;
      s_outf[(c4 + 1) * 49 + p] = a1;
      s_outf[(c4 + 2) * 49 + p] = a2;
      s_outf[(c4 + 3) * 49 + p] = a3;
    } else {
      s_outh[(c4 + 0) * 49 + p] = (half_t)a0;
      s_outh[(c4 + 1) * 49 + p] = (half_t)a1;
      s_outh[(c4 + 2) * 49 + p] = (half_t)a2;
      s_outh[(c4 + 3) * 49 + p] = (half_t)a3;
    }
  }
  __syncthreads();

  if (PASS2) {
    float* ob = out + (size_t)n * KDIM;
    for (int l = tid * 4; l < KDIM; l += 2048)
      *(float4*)(ob + l) = *(const float4*)(s_outf + l);
  } else {
    half_t* ob = xout + (size_t)n * KDIM;
    for (int l = tid * 8; l < KDIM; l += 4096)
      *(f16x8*)(ob + l) = *(const f16x8*)(s_outh + l);
  }
}

// ---- split-K fp16 MFMA GEMM, global_load_lds + counted vmcnt (T3/T4) ----
// 128x128 tile, BK=64, 256 thr / 4 waves, double-buffered LDS (64 KB, 2 blocks/CU).
// Staging: 8 global_load_lds DMAs per wave per K-step; LDS dest linear; bank
// swizzle on the GLOBAL SOURCE side (lane l loads chunk (l&7)^(l>>3)); ds_read
// XORs it back. Counted vmcnt(8) before raw s_barrier -- no vmcnt(0) in loop.
// XCD swizzle: per-XCD contiguous g range, z-major -> A/B K-slices stay in L2.
// P layout: [z][tile=by*4+bx][wave][q=(i*4+j)*4+rr][lane]
template <int SK>
__global__ __launch_bounds__(256, 2) void gemm_lds(const half_t* __restrict__ A,
                                                   const half_t* __restrict__ B,
                                                   float* __restrict__ P, int K) {
  __shared__ half_t As[2][128 * 64];   // 32 KB
  __shared__ half_t Bs[2][128 * 64];   // 32 KB
  const int d = blockIdx.x + gridDim.x * (blockIdx.y + gridDim.y * blockIdx.z);
  const int g = (d & 7) * (SK * 4) + (d >> 3);   // bijective: 32*SK blocks, %8==0
  const int z = g >> 5;          // 32 tiles per z-slice
  const int tile = g & 31;
  const int m0 = (tile & 3) * 128;
  const int n0 = (tile >> 2) * 128;
  const int Kc = K / SK;
  const int kbeg = z * Kc;
  const int tid = threadIdx.x;
  const int lane = tid & 63;
  const int wave = tid >> 6;
  const int wm = (wave & 1) * 64;
  const int wn = (wave >> 1) * 64;
  const int fr = lane & 15;
  const int kc0 = lane >> 4;              // 0..3
  // staging geometry: call s covers rows s*32 + wave*8 + (lane>>3)
  const int lr = lane >> 3;               // 0..7
  const int lc = (lane & 7) ^ lr;         // pre-swizzled global 16B-chunk
  const half_t* Ag = A + (size_t)(m0 + wave * 8 + lr) * K + kbeg + lc * 8;
  const half_t* Bg = B + (size_t)(n0 + wave * 8 + lr) * K + kbeg + lc * 8;
  f32x4 acc[4][4] = {};

  auto stage = [&](int buf, int ko) {
#pragma unroll
    for (int s = 0; s < 4; s++)
      gload16(Ag + (size_t)(32 * s) * K + ko, &As[buf][s * 2048 + wave * 512]);
#pragma unroll
    for (int s = 0; s < 4; s++)
      gload16(Bg + (size_t)(32 * s) * K + ko, &Bs[buf][s * 2048 + wave * 512]);
  };

  const int iters = Kc >> 6;
  // prologue: tile0 -> buf0; tile1 -> buf1 (stays in flight across barrier)
  stage(0, 0);
  if (iters > 1) {
    stage(1, 64);
    asm volatile("s_waitcnt vmcnt(8)" ::: "memory");   // buf0 complete, buf1 in flight
  } else {
    asm volatile("s_waitcnt vmcnt(0)" ::: "memory");
  }
  __builtin_amdgcn_s_barrier();

  for (int it = 0; it < iters; it++) {
    const int cur = it & 1;
#pragma unroll
    for (int ks = 0; ks < 2; ks++) {
      const int swz = ((kc0 + ks * 4) ^ (fr & 7)) * 8;
      f16x8 af[4], bf[4];
#pragma unroll
      for (int i = 0; i < 4; i++) af[i] = *(const f16x8*)&As[cur][(wm + i * 16 + fr) * 64 + swz];
#pragma unroll
      for (int j = 0; j < 4; j++) bf[j] = *(const f16x8*)&Bs[cur][(wn + j * 16 + fr) * 64 + swz];
#pragma unroll
      for (int i = 0; i < 4; i++)
#pragma unroll
        for (int j = 0; j < 4; j++)
          acc[i][j] = __builtin_amdgcn_mfma_f32_16x16x32_f16(af[i], bf[j], acc[i][j], 0, 0, 0);
    }
    // all my LDS reads done; all waves' reads done -> safe to re-stage buf[cur]
    asm volatile("s_waitcnt lgkmcnt(0)" ::: "memory");
    __builtin_amdgcn_s_barrier();
    const bool issue = (it + 2 < iters);
    if (issue) stage(cur, (it + 2) * 64);
    if (it + 1 < iters) {
      if (issue) asm volatile("s_waitcnt vmcnt(8)" ::: "memory");  // older batch only
      else       asm volatile("s_waitcnt vmcnt(0)" ::: "memory");  // nothing newer in flight
      __builtin_amdgcn_s_barrier();
    }
  }
  // blocked store: 256B contiguous per (q) store
  float* Pz = P + (((size_t)z * 32 + tile) * 4 + wave) * 4096;
#pragma unroll
  for (int i = 0; i < 4; i++)
#pragma unroll
    for (int j = 0; j < 4; j++)
#pragma unroll
      for (int rr = 0; rr < 4; rr++)
        Pz[((i * 4 + j) * 4 + rr) * 64 + lane] = acc[i][j][rr];
}

// ---- reduce SK blocked partials + bias (+relu), write fp16 or fp32 (128x128 layout) ----
template <bool OUT16, bool RELU, int SK>
__global__ __launch_bounds__(256) void reduce_blocked(const float* __restrict__ P,
                                                      const float* __restrict__ bias,
                                                      void* __restrict__ out,
                                                      int MN, int N) {
  int i4 = (blockIdx.x * 256 + threadIdx.x) * 4;
  if (i4 >= MN) return;
  float4 s = *(const float4*)(P + i4);
#pragma unroll
  for (int z = 1; z < SK; z++) {
    float4 t = *(const float4*)(P + (size_t)z * MN + i4);
    s.x += t.x; s.y += t.y; s.z += t.z; s.w += t.w;
  }
  const int lane0 = i4 & 63;
  const int q     = (i4 >> 6) & 63;
  const int wave  = (i4 >> 12) & 3;
  const int bx    = (i4 >> 14) & 3;
  const int by    = (i4 >> 16) & 7;
  const int rr = q & 3, j_ = (q >> 2) & 3, i_ = q >> 4;
  const int row = bx * 128 + (wave & 1) * 64 + i_ * 16 + (lane0 >> 4) * 4 + rr;
  const int col = by * 128 + (wave >> 1) * 64 + j_ * 16 + (lane0 & 15);
  float4 bv = *(const float4*)(bias + col);
  s.x += bv.x; s.y += bv.y; s.z += bv.z; s.w += bv.w;
  if (RELU) {
    s.x = fmaxf(s.x, 0.0f); s.y = fmaxf(s.y, 0.0f);
    s.z = fmaxf(s.z, 0.0f); s.w = fmaxf(s.w, 0.0f);
  }
  size_t o = (size_t)row * N + col;
  if (OUT16) {
    f16x4 ov;
    ov[0] = (half_t)s.x; ov[1] = (half_t)s.y; ov[2] = (half_t)s.z; ov[3] = (half_t)s.w;
    *(f16x4*)((half_t*)out + o) = ov;
  } else {
    *(float4*)((float*)out + o) = s;
  }
}

// ---- GEMM3 split-K partials: part3[z][n][147] = h2[n, z*128:(z+1)*128] @ w3^T ----
// 8 ROIs per block (w3 row chunk loaded once per 8 n's -> L2 traffic /8), 8
// independent accumulators (kills the serial FMA chain that made the old
// gemm_small latency-bound at VALUBusy 8%). hs reads are wave-broadcast ds_reads.
__global__ __launch_bounds__(192) void gemm3_part(const float* __restrict__ h2,
                                                  const float* __restrict__ w3,
                                                  float* __restrict__ part3) {
  __shared__ float hs[8][128];
  const int n0 = blockIdx.x * 8;
  const int z = blockIdx.y;
  const int tid = threadIdx.x;
  for (int idx = tid; idx < 1024; idx += 192) {
    int nn = idx >> 7, kk = idx & 127;
    hs[nn][kk] = h2[(size_t)(n0 + nn) * FC + z * 128 + kk];
  }
  __syncthreads();
  const int j = tid;
  if (j < 147) {
    const float* wr = w3 + (size_t)j * FC + z * 128;
    float acc[8] = {0, 0, 0, 0, 0, 0, 0, 0};
    for (int k = 0; k < 128; k += 4) {
      float4 wv = *(const float4*)(wr + k);
#pragma unroll
      for (int nn = 0; nn < 8; nn++)
        acc[nn] += hs[nn][k] * wv.x + hs[nn][k + 1] * wv.y +
                   hs[nn][k + 2] * wv.z + hs[nn][k + 3] * wv.w;
    }
#pragma unroll
    for (int nn = 0; nn < 8; nn++)
      part3[((size_t)z * NROI + n0 + nn) * 147 + j] = acc[nn];
  }
}

extern "C" void kernel_launch(void* const* d_in, const int* in_sizes, int n_in,
                              void* d_out, int out_size, void* d_ws, size_t ws_size,
                              hipStream_t stream) {
  const float* feat = (const float*)d_in[0];
  const float* rois = (const float*)d_in[1];
  const float* w1 = (const float*)d_in[2];
  const float* b1 = (const float*)d_in[3];
  const float* w2 = (const float*)d_in[4];
  const float* b2 = (const float*)d_in[5];
  const float* w3 = (const float*)d_in[6];
  const float* b3 = (const float*)d_in[7];
  float* out = (float*)d_out;
  char* ws = (char*)d_ws;

  // workspace carve (~83.7 MB total)
  half_t* featT = (half_t*)ws;                        // 10,240,000 B
  half_t* xh    = (half_t*)(ws + 10240000);           // 12,845,056 B  (k = c*49+p)
  half_t* w1h   = (half_t*)(ws + 23085056);           // 25,690,112 B  (raw layout)
  half_t* w2h   = (half_t*)(ws + 48775168);           //  2,097,152 B
  half_t* h1    = (half_t*)(ws + 50872320);           //  1,048,576 B
  float*  h2    = (float*)(ws + 51920896);            //  2,097,152 B
  float*  part  = (float*)(ws + 54319104);            // 29,360,128 B (also part3 after reduce2)

  const int MN = NROI * FC;  // 524288

  transpose_feat<<<dim3(313, 8, 2), dim3(32, 8), 0, stream>>>(feat, featT);
  convert_f32_f16<<<dim3(12544), dim3(256), 0, stream>>>(w1, w1h, FC * KDIM);
  convert_f32_f16<<<dim3(1024), dim3(256), 0, stream>>>(w2, w2h, FC * FC);
  pool_kernel<false><<<dim3(NROI), dim3(512), 0, stream>>>(featT, rois, nullptr, nullptr, xh, nullptr);

  // GEMM1: (512x12544) @ (1024x12544)^T -> 128x128 tiles, SK=14, 448 blocks, XCD-swizzled
  gemm_lds<14><<<dim3(4, 8, 14), dim3(256), 0, stream>>>(xh, w1h, part, KDIM);
  reduce_blocked<true, true, 14><<<dim3(MN / 1024), dim3(256), 0, stream>>>(part, b1, (void*)h1, MN, FC);

  // GEMM2: (512x1024) @ (1024x1024)^T -> SK=8, 256 blocks, XCD-swizzled
  gemm_lds<8><<<dim3(4, 8, 8), dim3(256), 0, stream>>>(h1, w2h, part, FC);
  reduce_blocked<false, true, 8><<<dim3(MN / 1024), dim3(256), 0, stream>>>(part, b2, (void*)h2, MN, FC);

  // GEMM3: split-K partials (reuses part ws); z-reduce + bias folded into pool pass 2
  gemm3_part<<<dim3(64, 8), dim3(192), 0, stream>>>(h2, w3, part);
  pool_kernel<true><<<dim3(NROI), dim3(512), 0, stream>>>(featT, rois, part, b3, nullptr, out);
}

// Round 6
// 225.805 us; speedup vs baseline: 1.3199x; 1.0158x over previous
//
#include <hip/hip_runtime.h>

// Problem constants (fixed by setup_inputs)
#define BB 2
#define CC 256
#define HH 100
#define WW 100
#define NROI 512
#define KDIM 12544   // 49*256
#define FC 1024

typedef _Float16 half_t;
typedef _Float16 f16x2 __attribute__((ext_vector_type(2)));
typedef _Float16 f16x8 __attribute__((ext_vector_type(8)));
typedef _Float16 f16x4 __attribute__((ext_vector_type(4)));
typedef float f32x4 __attribute__((ext_vector_type(4)));

// async global->LDS DMA, 16B per lane, wave-uniform LDS base + lane*16
__device__ __forceinline__ void gload16(const half_t* g, half_t* l) {
  __builtin_amdgcn_global_load_lds(
      (const __attribute__((address_space(1))) unsigned int*)g,
      (__attribute__((address_space(3))) unsigned int*)l, 16, 0, 0);
}

// ---------------- fused prep: w1/w2 fp32->fp16 converts + feat transpose ----------------
// One launch: overlaps the transpose tail with the 77 MB w1 convert, saves 2 launch gaps.
// blocks [0,12544): w1 conv; [12544,13568): w2 conv; [13568,18576): transpose.
__global__ __launch_bounds__(256) void prep(const float* __restrict__ feat,
                                            half_t* __restrict__ featT,
                                            const float* __restrict__ w1,
                                            half_t* __restrict__ w1h,
                                            const float* __restrict__ w2,
                                            half_t* __restrict__ w2h) {
  int bid = blockIdx.x;
  if (bid < 12544) {                       // w1: FC*KDIM = 12,845,056 elems
    int i4 = (bid * 256 + threadIdx.x) * 4;
    float4 v = *(const float4*)(w1 + i4);
    f16x4 o;
    o[0] = (half_t)v.x; o[1] = (half_t)v.y; o[2] = (half_t)v.z; o[3] = (half_t)v.w;
    *(f16x4*)(w1h + i4) = o;
    return;
  }
  bid -= 12544;
  if (bid < 1024) {                        // w2: FC*FC = 1,048,576 elems
    int i4 = (bid * 256 + threadIdx.x) * 4;
    float4 v = *(const float4*)(w2 + i4);
    f16x4 o;
    o[0] = (half_t)v.x; o[1] = (half_t)v.y; o[2] = (half_t)v.z; o[3] = (half_t)v.w;
    *(f16x4*)(w2h + i4) = o;
    return;
  }
  bid -= 1024;                             // transpose: 313*8*2 = 5008 blocks
  __shared__ float tile[32][33];
  const int bx = bid % 313;
  const int rem = bid / 313;
  const int by = rem & 7;
  const int bz = rem >> 3;
  const int tx = threadIdx.x & 31, ty = threadIdx.x >> 5;
  const int hw0 = bx * 32;
  const int c0 = by * 32;
  const float* fb = feat + (size_t)bz * CC * (HH * WW);
#pragma unroll
  for (int i = 0; i < 4; i++) {
    int c = c0 + ty + i * 8;
    int hw = hw0 + tx;
    tile[ty + i * 8][tx] = (hw < HH * WW) ? fb[(size_t)c * (HH * WW) + hw] : 0.0f;
  }
  __syncthreads();
  half_t* ob = featT + (size_t)bz * (HH * WW) * CC;
#pragma unroll
  for (int i = 0; i < 4; i++) {
    int hw = hw0 + ty + i * 8;
    int c = c0 + tx;
    if (hw < HH * WW) ob[(size_t)hw * CC + c] = (half_t)tile[tx][ty + i * 8];
  }
}

// ---------------- deformable PSROI pooling, one block (512 thr) per ROI ----------------
// PASS2: om values come as split-K partials part3[z][n][147]; z-reduce + b3 bias
// folded into phase 1 (24 scalar loads by 49 threads, off the block critical path).
// Phase 2: 8 gather loads in flight per wave (latency-bound L2/L3 gathers).
struct PixW { int idx; float w; };

template <bool PASS2>
__global__ __launch_bounds__(512) void pool_kernel(const half_t* __restrict__ featT,
                                                   const float* __restrict__ rois,
                                                   const float* __restrict__ part3,
                                                   const float* __restrict__ b3,
                                                   half_t* __restrict__ xout,
                                                   float* __restrict__ out) {
  __shared__ __align__(16) PixW s_pix[49 * 32];       // 12544 B (<=25 pixels, pad to x8)
  __shared__ int s_cnt[49];
  __shared__ float s_scale[49];
  __shared__ float  s_outf[PASS2 ? KDIM : 1];         // 50176 B (PASS2)
  __shared__ half_t s_outh[PASS2 ? 1 : KDIM];         // 25088 B (PASS1 -> 4 blocks/CU)

  const int n = blockIdx.x;
  const int tid = threadIdx.x;
  const float* r = rois + n * 5;
  const int b = (int)r[0];
  const float rsw = rintf(r[1]) * 0.0625f - 0.5f;
  const float rsh = rintf(r[2]) * 0.0625f - 0.5f;
  const float rew = (rintf(r[3]) + 1.0f) * 0.0625f - 0.5f;
  const float reh = (rintf(r[4]) + 1.0f) * 0.0625f - 0.5f;
  const float roi_w = fmaxf(rew - rsw, 0.1f);
  const float roi_h = fmaxf(reh - rsh, 0.1f);
  const float bin_h = roi_h / 7.0f, bin_w = roi_w / 7.0f;
  const float sub_h = bin_h * 0.25f, sub_w = bin_w * 0.25f;
  const half_t* fb = featT + (size_t)b * (HH * WW) * CC;

  if (tid < 49) {
    const int p = tid, ph = p / 7, pw = p - ph * 7;
    float tx = 0.0f, ty = 0.0f, mask = 1.0f;
    if (PASS2) {
      float o0 = b3[p], o1 = b3[49 + p], o2 = b3[98 + p];
#pragma unroll
      for (int zz = 0; zz < 8; zz++) {
        const float* pz = part3 + ((size_t)zz * NROI + n) * 147;
        o0 += pz[p]; o1 += pz[49 + p]; o2 += pz[98 + p];
      }
      tx = o0 * 0.1f;
      ty = o1 * 0.1f;
      mask = 1.0f / (1.0f + expf(-o2));
    }
    const float hst = (float)ph * bin_h + rsh + ty * roi_h;
    const float wst = (float)pw * bin_w + rsw + tx * roi_w;
    float wh[6] = {0, 0, 0, 0, 0, 0};
    float hc0 = fminf(fmaxf(hst, 0.0f), 99.0f);
    const int r0 = (int)hc0;
    int rtop = r0;
    float vsh = 0.0f;
#pragma unroll
    for (int i = 0; i < 4; i++) {
      float h = hst + (float)i * sub_h;
      bool v = (h >= -0.5f) && (h <= (float)HH - 0.5f);
      float hc = fminf(fmaxf(h, 0.0f), 99.0f);
      int h0 = (int)hc;
      float lh = hc - (float)h0;
      int h1 = min(h0 + 1, HH - 1);
      if (v) { wh[h0 - r0] += 1.0f - lh; wh[h1 - r0] += lh; vsh += 1.0f; }
      rtop = h1;
    }
    float wwc[6] = {0, 0, 0, 0, 0, 0};
    float wc0 = fminf(fmaxf(wst, 0.0f), 99.0f);
    const int c0 = (int)wc0;
    int ctop = c0;
    float vsw = 0.0f;
#pragma unroll
    for (int j = 0; j < 4; j++) {
      float w = wst + (float)j * sub_w;
      bool v = (w >= -0.5f) && (w <= (float)WW - 0.5f);
      float wc = fminf(fmaxf(w, 0.0f), 99.0f);
      int w0 = (int)wc;
      float lw = wc - (float)w0;
      int w1 = min(w0 + 1, WW - 1);
      if (v) { wwc[w0 - c0] += 1.0f - lw; wwc[w1 - c0] += lw; vsw += 1.0f; }
      ctop = w1;
    }
    const int nr = rtop - r0 + 1, nc = ctop - c0 + 1;
    float cntf = vsh * vsw;
    s_scale[p] = (cntf > 0.0f) ? mask / cntf : 0.0f;
    PixW* dst = &s_pix[p * 32];
    int m = 0;
    for (int ri = 0; ri < nr; ri++) {
      int rowoff = (r0 + ri) * WW + c0;
      for (int ci = 0; ci < nc; ci++) {
        dst[m].idx = (rowoff + ci) * CC;
        dst[m].w = wh[ri] * wwc[ci];
        m++;
      }
    }
    while (m & 7) { dst[m].idx = 0; dst[m].w = 0.0f; m++; }   // pad to mult of 8
    s_cnt[p] = m;
  }
  __syncthreads();

  // ---- phase 2: wave per bin, lane = 4 channels, 8 gather loads in flight ----
  const int wv = tid >> 6;
  const int c4 = (tid & 63) * 4;
  for (int p = wv; p < 49; p += 8) {
    const int cnt = __builtin_amdgcn_readfirstlane(s_cnt[p]);
    const PixW* cp = &s_pix[p * 32];
    float a0 = 0.0f, a1 = 0.0f, a2 = 0.0f, a3 = 0.0f;
    for (int q = 0; q < cnt; q += 8) {
      const uint4* cp4 = (const uint4*)(cp + q);      // broadcast LDS reads, 2 PixW each
      uint4 e0 = cp4[0], e1 = cp4[1], e2 = cp4[2], e3 = cp4[3];
      int i0 = __builtin_amdgcn_readfirstlane(e0.x);
      float sw0 = __uint_as_float(__builtin_amdgcn_readfirstlane(e0.y));
      int i1 = __builtin_amdgcn_readfirstlane(e0.z);
      float sw1 = __uint_as_float(__builtin_amdgcn_readfirstlane(e0.w));
      int i2 = __builtin_amdgcn_readfirstlane(e1.x);
      float sw2 = __uint_as_float(__builtin_amdgcn_readfirstlane(e1.y));
      int i3 = __builtin_amdgcn_readfirstlane(e1.z);
      float sw3 = __uint_as_float(__builtin_amdgcn_readfirstlane(e1.w));
      int i4_ = __builtin_amdgcn_readfirstlane(e2.x);
      float sw4 = __uint_as_float(__builtin_amdgcn_readfirstlane(e2.y));
      int i5 = __builtin_amdgcn_readfirstlane(e2.z);
      float sw5 = __uint_as_float(__builtin_amdgcn_readfirstlane(e2.w));
      int i6 = __builtin_amdgcn_readfirstlane(e3.x);
      float sw6 = __uint_as_float(__builtin_amdgcn_readfirstlane(e3.y));
      int i7 = __builtin_amdgcn_readfirstlane(e3.z);
      float sw7 = __uint_as_float(__builtin_amdgcn_readfirstlane(e3.w));
      f16x4 v0 = *(const f16x4*)(fb + i0 + c4);
      f16x4 v1 = *(const f16x4*)(fb + i1 + c4);
      f16x4 v2 = *(const f16x4*)(fb + i2 + c4);
      f16x4 v3 = *(const f16x4*)(fb + i3 + c4);
      f16x4 v4 = *(const f16x4*)(fb + i4_ + c4);
      f16x4 v5 = *(const f16x4*)(fb + i5 + c4);
      f16x4 v6 = *(const f16x4*)(fb + i6 + c4);
      f16x4 v7 = *(const f16x4*)(fb + i7 + c4);
      a0 += sw0 * (float)v0[0] + sw1 * (float)v1[0] + sw2 * (float)v2[0] + sw3 * (float)v3[0]
          + sw4 * (float)v4[0] + sw5 * (float)v5[0] + sw6 * (float)v6[0] + sw7 * (float)v7[0];
      a1 += sw0 * (float)v0[1] + sw1 * (float)v1[1] + sw2 * (float)v2[1] + sw3 * (float)v3[1]
          + sw4 * (float)v4[1] + sw5 * (float)v5[1] + sw6 * (float)v6[1] + sw7 * (float)v7[1];
      a2 += sw0 * (float)v0[2] + sw1 * (float)v1[2] + sw2 * (float)v2[2] + sw3 * (float)v3[2]
          + sw4 * (float)v4[2] + sw5 * (float)v5[2] + sw6 * (float)v6[2] + sw7 * (float)v7[2];
      a3 += sw0 * (float)v0[3] + sw1 * (float)v1[3] + sw2 * (float)v2[3] + sw3 * (float)v3[3]
          + sw4 * (float)v4[3] + sw5 * (float)v5[3] + sw6 * (float)v6[3] + sw7 * (float)v7[3];
    }
    float sc = s_scale[p];
    a0 *= sc; a1 *= sc; a2 *= sc; a3 *= sc;
    if (PASS2) {
      s_outf[(c4 + 0) * 49 + p] = a0;
      s_outf[(c4 + 1) * 49 + p] = a1;
      s_outf[(c4 + 2) * 49 + p] = a2;
      s_outf[(c4 + 3) * 49 + p] = a3;
    } else {
      s_outh[(c4 + 0) * 49 + p] = (half_t)a0;
      s_outh[(c4 + 1) * 49 + p] = (half_t)a1;
      s_outh[(c4 + 2) * 49 + p] = (half_t)a2;
      s_outh[(c4 + 3) * 49 + p] = (half_t)a3;
    }
  }
  __syncthreads();

  if (PASS2) {
    float* ob = out + (size_t)n * KDIM;
    for (int l = tid * 4; l < KDIM; l += 2048)
      *(float4*)(ob + l) = *(const float4*)(s_outf + l);
  } else {
    half_t* ob = xout + (size_t)n * KDIM;
    for (int l = tid * 8; l < KDIM; l += 4096)
      *(f16x8*)(ob + l) = *(const f16x8*)(s_outh + l);
  }
}

// ---- split-K fp16 MFMA GEMM, global_load_lds + counted vmcnt (T3/T4) ----
// 128x128 tile, BK=64, 256 thr / 4 waves, double-buffered LDS (64 KB, 2 blocks/CU).
// Staging: 8 global_load_lds DMAs per wave per K-step; LDS dest linear; bank
// swizzle on the GLOBAL SOURCE side (lane l loads chunk (l&7)^(l>>3)); ds_read
// XORs it back. Counted vmcnt(8) before raw s_barrier -- no vmcnt(0) in loop.
// XCD swizzle: per-XCD contiguous g range, z-major -> A/B K-slices stay in L2.
// P layout: [z][tile=by*4+bx][wave][q=(i*4+j)*4+rr][lane]
template <int SK>
__global__ __launch_bounds__(256, 2) void gemm_lds(const half_t* __restrict__ A,
                                                   const half_t* __restrict__ B,
                                                   float* __restrict__ P, int K) {
  __shared__ half_t As[2][128 * 64];   // 32 KB
  __shared__ half_t Bs[2][128 * 64];   // 32 KB
  const int d = blockIdx.x + gridDim.x * (blockIdx.y + gridDim.y * blockIdx.z);
  const int g = (d & 7) * (SK * 4) + (d >> 3);   // bijective: 32*SK blocks, %8==0
  const int z = g >> 5;          // 32 tiles per z-slice
  const int tile = g & 31;
  const int m0 = (tile & 3) * 128;
  const int n0 = (tile >> 2) * 128;
  const int Kc = K / SK;
  const int kbeg = z * Kc;
  const int tid = threadIdx.x;
  const int lane = tid & 63;
  const int wave = tid >> 6;
  const int wm = (wave & 1) * 64;
  const int wn = (wave >> 1) * 64;
  const int fr = lane & 15;
  const int kc0 = lane >> 4;              // 0..3
  // staging geometry: call s covers rows s*32 + wave*8 + (lane>>3)
  const int lr = lane >> 3;               // 0..7
  const int lc = (lane & 7) ^ lr;         // pre-swizzled global 16B-chunk
  const half_t* Ag = A + (size_t)(m0 + wave * 8 + lr) * K + kbeg + lc * 8;
  const half_t* Bg = B + (size_t)(n0 + wave * 8 + lr) * K + kbeg + lc * 8;
  f32x4 acc[4][4] = {};

  auto stage = [&](int buf, int ko) {
#pragma unroll
    for (int s = 0; s < 4; s++)
      gload16(Ag + (size_t)(32 * s) * K + ko, &As[buf][s * 2048 + wave * 512]);
#pragma unroll
    for (int s = 0; s < 4; s++)
      gload16(Bg + (size_t)(32 * s) * K + ko, &Bs[buf][s * 2048 + wave * 512]);
  };

  const int iters = Kc >> 6;
  // prologue: tile0 -> buf0; tile1 -> buf1 (stays in flight across barrier)
  stage(0, 0);
  if (iters > 1) {
    stage(1, 64);
    asm volatile("s_waitcnt vmcnt(8)" ::: "memory");   // buf0 complete, buf1 in flight
  } else {
    asm volatile("s_waitcnt vmcnt(0)" ::: "memory");
  }
  __builtin_amdgcn_s_barrier();

  for (int it = 0; it < iters; it++) {
    const int cur = it & 1;
#pragma unroll
    for (int ks = 0; ks < 2; ks++) {
      const int swz = ((kc0 + ks * 4) ^ (fr & 7)) * 8;
      f16x8 af[4], bf[4];
#pragma unroll
      for (int i = 0; i < 4; i++) af[i] = *(const f16x8*)&As[cur][(wm + i * 16 + fr) * 64 + swz];
#pragma unroll
      for (int j = 0; j < 4; j++) bf[j] = *(const f16x8*)&Bs[cur][(wn + j * 16 + fr) * 64 + swz];
#pragma unroll
      for (int i = 0; i < 4; i++)
#pragma unroll
        for (int j = 0; j < 4; j++)
          acc[i][j] = __builtin_amdgcn_mfma_f32_16x16x32_f16(af[i], bf[j], acc[i][j], 0, 0, 0);
    }
    // all my LDS reads done; all waves' reads done -> safe to re-stage buf[cur]
    asm volatile("s_waitcnt lgkmcnt(0)" ::: "memory");
    __builtin_amdgcn_s_barrier();
    const bool issue = (it + 2 < iters);
    if (issue) stage(cur, (it + 2) * 64);
    if (it + 1 < iters) {
      if (issue) asm volatile("s_waitcnt vmcnt(8)" ::: "memory");  // older batch only
      else       asm volatile("s_waitcnt vmcnt(0)" ::: "memory");  // nothing newer in flight
      __builtin_amdgcn_s_barrier();
    }
  }
  // blocked store: 256B contiguous per (q) store
  float* Pz = P + (((size_t)z * 32 + tile) * 4 + wave) * 4096;
#pragma unroll
  for (int i = 0; i < 4; i++)
#pragma unroll
    for (int j = 0; j < 4; j++)
#pragma unroll
      for (int rr = 0; rr < 4; rr++)
        Pz[((i * 4 + j) * 4 + rr) * 64 + lane] = acc[i][j][rr];
}

// ---- reduce SK blocked partials + bias (+relu), write fp16 or fp32 (128x128 layout) ----
template <bool OUT16, bool RELU, int SK>
__global__ __launch_bounds__(256) void reduce_blocked(const float* __restrict__ P,
                                                      const float* __restrict__ bias,
                                                      void* __restrict__ out,
                                                      int MN, int N) {
  int i4 = (blockIdx.x * 256 + threadIdx.x) * 4;
  if (i4 >= MN) return;
  float4 s = *(const float4*)(P + i4);
#pragma unroll
  for (int z = 1; z < SK; z++) {
    float4 t = *(const float4*)(P + (size_t)z * MN + i4);
    s.x += t.x; s.y += t.y; s.z += t.z; s.w += t.w;
  }
  const int lane0 = i4 & 63;
  const int q     = (i4 >> 6) & 63;
  const int wave  = (i4 >> 12) & 3;
  const int bx    = (i4 >> 14) & 3;
  const int by    = (i4 >> 16) & 7;
  const int rr = q & 3, j_ = (q >> 2) & 3, i_ = q >> 4;
  const int row = bx * 128 + (wave & 1) * 64 + i_ * 16 + (lane0 >> 4) * 4 + rr;
  const int col = by * 128 + (wave >> 1) * 64 + j_ * 16 + (lane0 & 15);
  float4 bv = *(const float4*)(bias + col);
  s.x += bv.x; s.y += bv.y; s.z += bv.z; s.w += bv.w;
  if (RELU) {
    s.x = fmaxf(s.x, 0.0f); s.y = fmaxf(s.y, 0.0f);
    s.z = fmaxf(s.z, 0.0f); s.w = fmaxf(s.w, 0.0f);
  }
  size_t o = (size_t)row * N + col;
  if (OUT16) {
    f16x4 ov;
    ov[0] = (half_t)s.x; ov[1] = (half_t)s.y; ov[2] = (half_t)s.z; ov[3] = (half_t)s.w;
    *(f16x4*)((half_t*)out + o) = ov;
  } else {
    *(float4*)((float*)out + o) = s;
  }
}

// ---- GEMM3 split-K partials: part3[z][n][147] = h2[n, z*128:(z+1)*128] @ w3^T ----
__global__ __launch_bounds__(192) void gemm3_part(const float* __restrict__ h2,
                                                  const float* __restrict__ w3,
                                                  float* __restrict__ part3) {
  __shared__ float hs[8][128];
  const int n0 = blockIdx.x * 8;
  const int z = blockIdx.y;
  const int tid = threadIdx.x;
  for (int idx = tid; idx < 1024; idx += 192) {
    int nn = idx >> 7, kk = idx & 127;
    hs[nn][kk] = h2[(size_t)(n0 + nn) * FC + z * 128 + kk];
  }
  __syncthreads();
  const int j = tid;
  if (j < 147) {
    const float* wr = w3 + (size_t)j * FC + z * 128;
    float acc[8] = {0, 0, 0, 0, 0, 0, 0, 0};
    for (int k = 0; k < 128; k += 4) {
      float4 wv = *(const float4*)(wr + k);
#pragma unroll
      for (int nn = 0; nn < 8; nn++)
        acc[nn] += hs[nn][k] * wv.x + hs[nn][k + 1] * wv.y +
                   hs[nn][k + 2] * wv.z + hs[nn][k + 3] * wv.w;
    }
#pragma unroll
    for (int nn = 0; nn < 8; nn++)
      part3[((size_t)z * NROI + n0 + nn) * 147 + j] = acc[nn];
  }
}

extern "C" void kernel_launch(void* const* d_in, const int* in_sizes, int n_in,
                              void* d_out, int out_size, void* d_ws, size_t ws_size,
                              hipStream_t stream) {
  const float* feat = (const float*)d_in[0];
  const float* rois = (const float*)d_in[1];
  const float* w1 = (const float*)d_in[2];
  const float* b1 = (const float*)d_in[3];
  const float* w2 = (const float*)d_in[4];
  const float* b2 = (const float*)d_in[5];
  const float* w3 = (const float*)d_in[6];
  const float* b3 = (const float*)d_in[7];
  float* out = (float*)d_out;
  char* ws = (char*)d_ws;

  // workspace carve (~83.7 MB total)
  half_t* featT = (half_t*)ws;                        // 10,240,000 B
  half_t* xh    = (half_t*)(ws + 10240000);           // 12,845,056 B  (k = c*49+p)
  half_t* w1h   = (half_t*)(ws + 23085056);           // 25,690,112 B  (raw layout)
  half_t* w2h   = (half_t*)(ws + 48775168);           //  2,097,152 B
  half_t* h1    = (half_t*)(ws + 50872320);           //  1,048,576 B
  float*  h2    = (float*)(ws + 51920896);            //  2,097,152 B
  float*  part  = (float*)(ws + 54319104);            // 29,360,128 B (also part3 after reduce2)

  const int MN = NROI * FC;  // 524288

  prep<<<dim3(18576), dim3(256), 0, stream>>>(feat, featT, w1, w1h, w2, w2h);
  pool_kernel<false><<<dim3(NROI), dim3(512), 0, stream>>>(featT, rois, nullptr, nullptr, xh, nullptr);

  // GEMM1: (512x12544) @ (1024x12544)^T -> 128x128 tiles, SK=14, 448 blocks, XCD-swizzled
  gemm_lds<14><<<dim3(4, 8, 14), dim3(256), 0, stream>>>(xh, w1h, part, KDIM);
  reduce_blocked<true, true, 14><<<dim3(MN / 1024), dim3(256), 0, stream>>>(part, b1, (void*)h1, MN, FC);

  // GEMM2: (512x1024) @ (1024x1024)^T -> SK=8, 256 blocks, XCD-swizzled
  gemm_lds<8><<<dim3(4, 8, 8), dim3(256), 0, stream>>>(h1, w2h, part, FC);
  reduce_blocked<false, true, 8><<<dim3(MN / 1024), dim3(256), 0, stream>>>(part, b2, (void*)h2, MN, FC);

  // GEMM3: split-K partials (reuses part ws); z-reduce + bias folded into pool pass 2
  gemm3_part<<<dim3(64, 8), dim3(192), 0, stream>>>(h2, w3, part);
  pool_kernel<true><<<dim3(NROI), dim3(512), 0, stream>>>(featT, rois, part, b3, nullptr, out);
}

// Round 7
// 220.317 us; speedup vs baseline: 1.3528x; 1.0249x over previous
//
#include <hip/hip_runtime.h>

// Problem constants (fixed by setup_inputs)
#define BB 2
#define CC 256
#define HH 100
#define WW 100
#define NROI 512
#define KDIM 12544   // 49*256
#define FC 1024

typedef _Float16 half_t;
typedef _Float16 f16x2 __attribute__((ext_vector_type(2)));
typedef _Float16 f16x8 __attribute__((ext_vector_type(8)));
typedef _Float16 f16x4 __attribute__((ext_vector_type(4)));
typedef float f32x4 __attribute__((ext_vector_type(4)));

// async global->LDS DMA, 16B per lane, wave-uniform LDS base + lane*16
__device__ __forceinline__ void gload16(const half_t* g, half_t* l) {
  __builtin_amdgcn_global_load_lds(
      (const __attribute__((address_space(1))) unsigned int*)g,
      (__attribute__((address_space(3))) unsigned int*)l, 16, 0, 0);
}

// ---------------- fused prep: w1/w2 fp32->fp16 converts + feat transpose ----------------
// blocks [0,12544): w1 conv; [12544,13568): w2 conv; [13568,18576): transpose.
__global__ __launch_bounds__(256) void prep(const float* __restrict__ feat,
                                            half_t* __restrict__ featT,
                                            const float* __restrict__ w1,
                                            half_t* __restrict__ w1h,
                                            const float* __restrict__ w2,
                                            half_t* __restrict__ w2h) {
  int bid = blockIdx.x;
  if (bid < 12544) {                       // w1: FC*KDIM = 12,845,056 elems
    int i4 = (bid * 256 + threadIdx.x) * 4;
    float4 v = *(const float4*)(w1 + i4);
    f16x4 o;
    o[0] = (half_t)v.x; o[1] = (half_t)v.y; o[2] = (half_t)v.z; o[3] = (half_t)v.w;
    *(f16x4*)(w1h + i4) = o;
    return;
  }
  bid -= 12544;
  if (bid < 1024) {                        // w2: FC*FC = 1,048,576 elems
    int i4 = (bid * 256 + threadIdx.x) * 4;
    float4 v = *(const float4*)(w2 + i4);
    f16x4 o;
    o[0] = (half_t)v.x; o[1] = (half_t)v.y; o[2] = (half_t)v.z; o[3] = (half_t)v.w;
    *(f16x4*)(w2h + i4) = o;
    return;
  }
  bid -= 1024;                             // transpose: 313*8*2 = 5008 blocks
  __shared__ float tile[32][33];
  const int bx = bid % 313;
  const int rem = bid / 313;
  const int by = rem & 7;
  const int bz = rem >> 3;
  const int tx = threadIdx.x & 31, ty = threadIdx.x >> 5;
  const int hw0 = bx * 32;
  const int c0 = by * 32;
  const float* fb = feat + (size_t)bz * CC * (HH * WW);
#pragma unroll
  for (int i = 0; i < 4; i++) {
    int c = c0 + ty + i * 8;
    int hw = hw0 + tx;
    tile[ty + i * 8][tx] = (hw < HH * WW) ? fb[(size_t)c * (HH * WW) + hw] : 0.0f;
  }
  __syncthreads();
  half_t* ob = featT + (size_t)bz * (HH * WW) * CC;
#pragma unroll
  for (int i = 0; i < 4; i++) {
    int hw = hw0 + ty + i * 8;
    int c = c0 + tx;
    if (hw < HH * WW) ob[(size_t)hw * CC + c] = (half_t)tile[tx][ty + i * 8];
  }
}

// ---------------- deformable PSROI pooling, one block (512 thr) per ROI ----------------
// PASS2: om values come as split-K partials part3[z][n][147]; z-reduce + b3 bias
// folded into phase 1. Phase 2: lane = (pixel-half, 8 channels) -> 2 pixels per
// f16x8 gather (1 KB/instr, coalescing sweet spot), no scalar readfirstlane chain;
// per-lane weights from 2-way-broadcast LDS reads (free); cross-half combine via
// one shfl_xor(32) per accumulator at bin end.
struct PixW { int idx; float w; };

template <bool PASS2>
__global__ __launch_bounds__(512) void pool_kernel(const half_t* __restrict__ featT,
                                                   const float* __restrict__ rois,
                                                   const float* __restrict__ part3,
                                                   const float* __restrict__ b3,
                                                   half_t* __restrict__ xout,
                                                   float* __restrict__ out) {
  __shared__ __align__(16) PixW s_pix[49 * 32];       // 12544 B (<=25 pixels, pad to x8)
  __shared__ int s_cnt[49];
  __shared__ float s_scale[49];
  __shared__ float  s_outf[PASS2 ? KDIM : 1];         // 50176 B (PASS2)
  __shared__ half_t s_outh[PASS2 ? 1 : KDIM];         // 25088 B (PASS1 -> 4 blocks/CU)

  const int n = blockIdx.x;
  const int tid = threadIdx.x;
  const float* r = rois + n * 5;
  const int b = (int)r[0];
  const float rsw = rintf(r[1]) * 0.0625f - 0.5f;
  const float rsh = rintf(r[2]) * 0.0625f - 0.5f;
  const float rew = (rintf(r[3]) + 1.0f) * 0.0625f - 0.5f;
  const float reh = (rintf(r[4]) + 1.0f) * 0.0625f - 0.5f;
  const float roi_w = fmaxf(rew - rsw, 0.1f);
  const float roi_h = fmaxf(reh - rsh, 0.1f);
  const float bin_h = roi_h / 7.0f, bin_w = roi_w / 7.0f;
  const float sub_h = bin_h * 0.25f, sub_w = bin_w * 0.25f;
  const half_t* fb = featT + (size_t)b * (HH * WW) * CC;

  if (tid < 49) {
    const int p = tid, ph = p / 7, pw = p - ph * 7;
    float tx = 0.0f, ty = 0.0f, mask = 1.0f;
    if (PASS2) {
      float o0 = b3[p], o1 = b3[49 + p], o2 = b3[98 + p];
#pragma unroll
      for (int zz = 0; zz < 8; zz++) {
        const float* pz = part3 + ((size_t)zz * NROI + n) * 147;
        o0 += pz[p]; o1 += pz[49 + p]; o2 += pz[98 + p];
      }
      tx = o0 * 0.1f;
      ty = o1 * 0.1f;
      mask = 1.0f / (1.0f + expf(-o2));
    }
    const float hst = (float)ph * bin_h + rsh + ty * roi_h;
    const float wst = (float)pw * bin_w + rsw + tx * roi_w;
    float wh[6] = {0, 0, 0, 0, 0, 0};
    float hc0 = fminf(fmaxf(hst, 0.0f), 99.0f);
    const int r0 = (int)hc0;
    int rtop = r0;
    float vsh = 0.0f;
#pragma unroll
    for (int i = 0; i < 4; i++) {
      float h = hst + (float)i * sub_h;
      bool v = (h >= -0.5f) && (h <= (float)HH - 0.5f);
      float hc = fminf(fmaxf(h, 0.0f), 99.0f);
      int h0 = (int)hc;
      float lh = hc - (float)h0;
      int h1 = min(h0 + 1, HH - 1);
      if (v) { wh[h0 - r0] += 1.0f - lh; wh[h1 - r0] += lh; vsh += 1.0f; }
      rtop = h1;
    }
    float wwc[6] = {0, 0, 0, 0, 0, 0};
    float wc0 = fminf(fmaxf(wst, 0.0f), 99.0f);
    const int c0 = (int)wc0;
    int ctop = c0;
    float vsw = 0.0f;
#pragma unroll
    for (int j = 0; j < 4; j++) {
      float w = wst + (float)j * sub_w;
      bool v = (w >= -0.5f) && (w <= (float)WW - 0.5f);
      float wc = fminf(fmaxf(w, 0.0f), 99.0f);
      int w0 = (int)wc;
      float lw = wc - (float)w0;
      int w1 = min(w0 + 1, WW - 1);
      if (v) { wwc[w0 - c0] += 1.0f - lw; wwc[w1 - c0] += lw; vsw += 1.0f; }
      ctop = w1;
    }
    const int nr = rtop - r0 + 1, nc = ctop - c0 + 1;
    float cntf = vsh * vsw;
    s_scale[p] = (cntf > 0.0f) ? mask / cntf : 0.0f;
    PixW* dst = &s_pix[p * 32];
    int m = 0;
    for (int ri = 0; ri < nr; ri++) {
      int rowoff = (r0 + ri) * WW + c0;
      for (int ci = 0; ci < nc; ci++) {
        dst[m].idx = (rowoff + ci) * CC;
        dst[m].w = wh[ri] * wwc[ci];
        m++;
      }
    }
    while (m & 7) { dst[m].idx = 0; dst[m].w = 0.0f; m++; }   // pad to mult of 8
    s_cnt[p] = m;
  }
  __syncthreads();

  // ---- phase 2: wave per bin; lane = (pixel-half, 8 channels); 4 pair-gathers in flight ----
  const int wv = tid >> 6;
  const int lane = tid & 63;
  const int half = lane >> 5;              // 0: even pixel, 1: odd pixel
  const int c8 = (lane & 31) * 8;          // 8 channels per lane, 32 lanes = 256 ch
  for (int p = wv; p < 49; p += 8) {
    const int cnt = s_cnt[p];              // wave-uniform LDS read
    const PixW* cp = &s_pix[p * 32];
    float a0 = 0, a1 = 0, a2 = 0, a3 = 0, a4 = 0, a5 = 0, a6 = 0, a7 = 0;
    for (int q = 0; q < cnt; q += 8) {
      PixW e0 = cp[q + 0 + half];          // 2-way broadcast (free)
      PixW e1 = cp[q + 2 + half];
      PixW e2 = cp[q + 4 + half];
      PixW e3 = cp[q + 6 + half];
      f16x8 v0 = *(const f16x8*)(fb + e0.idx + c8);
      f16x8 v1 = *(const f16x8*)(fb + e1.idx + c8);
      f16x8 v2 = *(const f16x8*)(fb + e2.idx + c8);
      f16x8 v3 = *(const f16x8*)(fb + e3.idx + c8);
      a0 += e0.w * (float)v0[0] + e1.w * (float)v1[0] + e2.w * (float)v2[0] + e3.w * (float)v3[0];
      a1 += e0.w * (float)v0[1] + e1.w * (float)v1[1] + e2.w * (float)v2[1] + e3.w * (float)v3[1];
      a2 += e0.w * (float)v0[2] + e1.w * (float)v1[2] + e2.w * (float)v2[2] + e3.w * (float)v3[2];
      a3 += e0.w * (float)v0[3] + e1.w * (float)v1[3] + e2.w * (float)v2[3] + e3.w * (float)v3[3];
      a4 += e0.w * (float)v0[4] + e1.w * (float)v1[4] + e2.w * (float)v2[4] + e3.w * (float)v3[4];
      a5 += e0.w * (float)v0[5] + e1.w * (float)v1[5] + e2.w * (float)v2[5] + e3.w * (float)v3[5];
      a6 += e0.w * (float)v0[6] + e1.w * (float)v1[6] + e2.w * (float)v2[6] + e3.w * (float)v3[6];
      a7 += e0.w * (float)v0[7] + e1.w * (float)v1[7] + e2.w * (float)v2[7] + e3.w * (float)v3[7];
    }
    // combine even/odd pixel halves (lanes l and l+32 hold same channels)
    a0 += __shfl_xor(a0, 32); a1 += __shfl_xor(a1, 32);
    a2 += __shfl_xor(a2, 32); a3 += __shfl_xor(a3, 32);
    a4 += __shfl_xor(a4, 32); a5 += __shfl_xor(a5, 32);
    a6 += __shfl_xor(a6, 32); a7 += __shfl_xor(a7, 32);
    if (half == 0) {
      float sc = s_scale[p];
      a0 *= sc; a1 *= sc; a2 *= sc; a3 *= sc; a4 *= sc; a5 *= sc; a6 *= sc; a7 *= sc;
      if (PASS2) {
        s_outf[(c8 + 0) * 49 + p] = a0;
        s_outf[(c8 + 1) * 49 + p] = a1;
        s_outf[(c8 + 2) * 49 + p] = a2;
        s_outf[(c8 + 3) * 49 + p] = a3;
        s_outf[(c8 + 4) * 49 + p] = a4;
        s_outf[(c8 + 5) * 49 + p] = a5;
        s_outf[(c8 + 6) * 49 + p] = a6;
        s_outf[(c8 + 7) * 49 + p] = a7;
      } else {
        s_outh[(c8 + 0) * 49 + p] = (half_t)a0;
        s_outh[(c8 + 1) * 49 + p] = (half_t)a1;
        s_outh[(c8 + 2) * 49 + p] = (half_t)a2;
        s_outh[(c8 + 3) * 49 + p] = (half_t)a3;
        s_outh[(c8 + 4) * 49 + p] = (half_t)a4;
        s_outh[(c8 + 5) * 49 + p] = (half_t)a5;
        s_outh[(c8 + 6) * 49 + p] = (half_t)a6;
        s_outh[(c8 + 7) * 49 + p] = (half_t)a7;
      }
    }
  }
  __syncthreads();

  if (PASS2) {
    float* ob = out + (size_t)n * KDIM;
    for (int l = tid * 4; l < KDIM; l += 2048)
      *(float4*)(ob + l) = *(const float4*)(s_outf + l);
  } else {
    half_t* ob = xout + (size_t)n * KDIM;
    for (int l = tid * 8; l < KDIM; l += 4096)
      *(f16x8*)(ob + l) = *(const f16x8*)(s_outh + l);
  }
}

// ---- split-K fp16 MFMA GEMM, global_load_lds + counted vmcnt (T3/T4) + T5 setprio ----
// 128x128 tile, BK=64, 256 thr / 4 waves, double-buffered LDS (64 KB, 2 blocks/CU).
// Staging: 8 global_load_lds DMAs per wave per K-step; LDS dest linear; bank
// swizzle on the GLOBAL SOURCE side; ds_read XORs it back. Counted vmcnt(8)
// before raw s_barrier -- no vmcnt(0) in loop. XCD swizzle keeps z-slices in L2.
// P layout: [z][tile=by*4+bx][wave][q=(i*4+j)*4+rr][lane]
template <int SK>
__global__ __launch_bounds__(256, 2) void gemm_lds(const half_t* __restrict__ A,
                                                   const half_t* __restrict__ B,
                                                   float* __restrict__ P, int K) {
  __shared__ half_t As[2][128 * 64];   // 32 KB
  __shared__ half_t Bs[2][128 * 64];   // 32 KB
  const int d = blockIdx.x + gridDim.x * (blockIdx.y + gridDim.y * blockIdx.z);
  const int g = (d & 7) * (SK * 4) + (d >> 3);   // bijective: 32*SK blocks, %8==0
  const int z = g >> 5;          // 32 tiles per z-slice
  const int tile = g & 31;
  const int m0 = (tile & 3) * 128;
  const int n0 = (tile >> 2) * 128;
  const int Kc = K / SK;
  const int kbeg = z * Kc;
  const int tid = threadIdx.x;
  const int lane = tid & 63;
  const int wave = tid >> 6;
  const int wm = (wave & 1) * 64;
  const int wn = (wave >> 1) * 64;
  const int fr = lane & 15;
  const int kc0 = lane >> 4;              // 0..3
  // staging geometry: call s covers rows s*32 + wave*8 + (lane>>3)
  const int lr = lane >> 3;               // 0..7
  const int lc = (lane & 7) ^ lr;         // pre-swizzled global 16B-chunk
  const half_t* Ag = A + (size_t)(m0 + wave * 8 + lr) * K + kbeg + lc * 8;
  const half_t* Bg = B + (size_t)(n0 + wave * 8 + lr) * K + kbeg + lc * 8;
  f32x4 acc[4][4] = {};

  auto stage = [&](int buf, int ko) {
#pragma unroll
    for (int s = 0; s < 4; s++)
      gload16(Ag + (size_t)(32 * s) * K + ko, &As[buf][s * 2048 + wave * 512]);
#pragma unroll
    for (int s = 0; s < 4; s++)
      gload16(Bg + (size_t)(32 * s) * K + ko, &Bs[buf][s * 2048 + wave * 512]);
  };

  const int iters = Kc >> 6;
  // prologue: tile0 -> buf0; tile1 -> buf1 (stays in flight across barrier)
  stage(0, 0);
  if (iters > 1) {
    stage(1, 64);
    asm volatile("s_waitcnt vmcnt(8)" ::: "memory");   // buf0 complete, buf1 in flight
  } else {
    asm volatile("s_waitcnt vmcnt(0)" ::: "memory");
  }
  __builtin_amdgcn_s_barrier();

  for (int it = 0; it < iters; it++) {
    const int cur = it & 1;
#pragma unroll
    for (int ks = 0; ks < 2; ks++) {
      const int swz = ((kc0 + ks * 4) ^ (fr & 7)) * 8;
      f16x8 af[4], bf[4];
#pragma unroll
      for (int i = 0; i < 4; i++) af[i] = *(const f16x8*)&As[cur][(wm + i * 16 + fr) * 64 + swz];
#pragma unroll
      for (int j = 0; j < 4; j++) bf[j] = *(const f16x8*)&Bs[cur][(wn + j * 16 + fr) * 64 + swz];
      __builtin_amdgcn_s_setprio(1);
#pragma unroll
      for (int i = 0; i < 4; i++)
#pragma unroll
        for (int j = 0; j < 4; j++)
          acc[i][j] = __builtin_amdgcn_mfma_f32_16x16x32_f16(af[i], bf[j], acc[i][j], 0, 0, 0);
      __builtin_amdgcn_s_setprio(0);
    }
    // all my LDS reads done; all waves' reads done -> safe to re-stage buf[cur]
    asm volatile("s_waitcnt lgkmcnt(0)" ::: "memory");
    __builtin_amdgcn_s_barrier();
    const bool issue = (it + 2 < iters);
    if (issue) stage(cur, (it + 2) * 64);
    if (it + 1 < iters) {
      if (issue) asm volatile("s_waitcnt vmcnt(8)" ::: "memory");  // older batch only
      else       asm volatile("s_waitcnt vmcnt(0)" ::: "memory");  // nothing newer in flight
      __builtin_amdgcn_s_barrier();
    }
  }
  // blocked store: 256B contiguous per (q) store
  float* Pz = P + (((size_t)z * 32 + tile) * 4 + wave) * 4096;
#pragma unroll
  for (int i = 0; i < 4; i++)
#pragma unroll
    for (int j = 0; j < 4; j++)
#pragma unroll
      for (int rr = 0; rr < 4; rr++)
        Pz[((i * 4 + j) * 4 + rr) * 64 + lane] = acc[i][j][rr];
}

// ---- reduce SK blocked partials + bias (+relu), write fp16 or fp32 (128x128 layout) ----
template <bool OUT16, bool RELU, int SK>
__global__ __launch_bounds__(256) void reduce_blocked(const float* __restrict__ P,
                                                      const float* __restrict__ bias,
                                                      void* __restrict__ out,
                                                      int MN, int N) {
  int i4 = (blockIdx.x * 256 + threadIdx.x) * 4;
  if (i4 >= MN) return;
  float4 s = *(const float4*)(P + i4);
#pragma unroll
  for (int z = 1; z < SK; z++) {
    float4 t = *(const float4*)(P + (size_t)z * MN + i4);
    s.x += t.x; s.y += t.y; s.z += t.z; s.w += t.w;
  }
  const int lane0 = i4 & 63;
  const int q     = (i4 >> 6) & 63;
  const int wave  = (i4 >> 12) & 3;
  const int bx    = (i4 >> 14) & 3;
  const int by    = (i4 >> 16) & 7;
  const int rr = q & 3, j_ = (q >> 2) & 3, i_ = q >> 4;
  const int row = bx * 128 + (wave & 1) * 64 + i_ * 16 + (lane0 >> 4) * 4 + rr;
  const int col = by * 128 + (wave >> 1) * 64 + j_ * 16 + (lane0 & 15);
  float4 bv = *(const float4*)(bias + col);
  s.x += bv.x; s.y += bv.y; s.z += bv.z; s.w += bv.w;
  if (RELU) {
    s.x = fmaxf(s.x, 0.0f); s.y = fmaxf(s.y, 0.0f);
    s.z = fmaxf(s.z, 0.0f); s.w = fmaxf(s.w, 0.0f);
  }
  size_t o = (size_t)row * N + col;
  if (OUT16) {
    f16x4 ov;
    ov[0] = (half_t)s.x; ov[1] = (half_t)s.y; ov[2] = (half_t)s.z; ov[3] = (half_t)s.w;
    *(f16x4*)((half_t*)out + o) = ov;
  } else {
    *(float4*)((float*)out + o) = s;
  }
}

// ---- GEMM3 split-K partials: part3[z][n][147] = h2[n, z*128:(z+1)*128] @ w3^T ----
__global__ __launch_bounds__(192) void gemm3_part(const float* __restrict__ h2,
                                                  const float* __restrict__ w3,
                                                  float* __restrict__ part3) {
  __shared__ float hs[8][128];
  const int n0 = blockIdx.x * 8;
  const int z = blockIdx.y;
  const int tid = threadIdx.x;
  for (int idx = tid; idx < 1024; idx += 192) {
    int nn = idx >> 7, kk = idx & 127;
    hs[nn][kk] = h2[(size_t)(n0 + nn) * FC + z * 128 + kk];
  }
  __syncthreads();
  const int j = tid;
  if (j < 147) {
    const float* wr = w3 + (size_t)j * FC + z * 128;
    float acc[8] = {0, 0, 0, 0, 0, 0, 0, 0};
    for (int k = 0; k < 128; k += 4) {
      float4 wv = *(const float4*)(wr + k);
#pragma unroll
      for (int nn = 0; nn < 8; nn++)
        acc[nn] += hs[nn][k] * wv.x + hs[nn][k + 1] * wv.y +
                   hs[nn][k + 2] * wv.z + hs[nn][k + 3] * wv.w;
    }
#pragma unroll
    for (int nn = 0; nn < 8; nn++)
      part3[((size_t)z * NROI + n0 + nn) * 147 + j] = acc[nn];
  }
}

extern "C" void kernel_launch(void* const* d_in, const int* in_sizes, int n_in,
                              void* d_out, int out_size, void* d_ws, size_t ws_size,
                              hipStream_t stream) {
  const float* feat = (const float*)d_in[0];
  const float* rois = (const float*)d_in[1];
  const float* w1 = (const float*)d_in[2];
  const float* b1 = (const float*)d_in[3];
  const float* w2 = (const float*)d_in[4];
  const float* b2 = (const float*)d_in[5];
  const float* w3 = (const float*)d_in[6];
  const float* b3 = (const float*)d_in[7];
  float* out = (float*)d_out;
  char* ws = (char*)d_ws;

  // workspace carve (~83.7 MB total)
  half_t* featT = (half_t*)ws;                        // 10,240,000 B
  half_t* xh    = (half_t*)(ws + 10240000);           // 12,845,056 B  (k = c*49+p)
  half_t* w1h   = (half_t*)(ws + 23085056);           // 25,690,112 B  (raw layout)
  half_t* w2h   = (half_t*)(ws + 48775168);           //  2,097,152 B
  half_t* h1    = (half_t*)(ws + 50872320);           //  1,048,576 B
  float*  h2    = (float*)(ws + 51920896);            //  2,097,152 B
  float*  part  = (float*)(ws + 54319104);            // 29,360,128 B (also part3 after reduce2)

  const int MN = NROI * FC;  // 524288

  prep<<<dim3(18576), dim3(256), 0, stream>>>(feat, featT, w1, w1h, w2, w2h);
  pool_kernel<false><<<dim3(NROI), dim3(512), 0, stream>>>(featT, rois, nullptr, nullptr, xh, nullptr);

  // GEMM1: (512x12544) @ (1024x12544)^T -> 128x128 tiles, SK=14, 448 blocks, XCD-swizzled
  gemm_lds<14><<<dim3(4, 8, 14), dim3(256), 0, stream>>>(xh, w1h, part, KDIM);
  reduce_blocked<true, true, 14><<<dim3(MN / 1024), dim3(256), 0, stream>>>(part, b1, (void*)h1, MN, FC);

  // GEMM2: (512x1024) @ (1024x1024)^T -> SK=8, 256 blocks, XCD-swizzled
  gemm_lds<8><<<dim3(4, 8, 8), dim3(256), 0, stream>>>(h1, w2h, part, FC);
  reduce_blocked<false, true, 8><<<dim3(MN / 1024), dim3(256), 0, stream>>>(part, b2, (void*)h2, MN, FC);

  // GEMM3: split-K partials (reuses part ws); z-reduce + bias folded into pool pass 2
  gemm3_part<<<dim3(64, 8), dim3(192), 0, stream>>>(h2, w3, part);
  pool_kernel<true><<<dim3(NROI), dim3(512), 0, stream>>>(featT, rois, part, b3, nullptr, out);
}